// Round 8
// baseline (333.778 us; speedup 1.0000x reference)
//
#include <hip/hip_runtime.h>
#include <hip/hip_bf16.h>

// Problem constants
#define BB 8
#define SS 1024
#define HH 512
#define DD 64

typedef unsigned short u16;
typedef short v8s __attribute__((ext_vector_type(8)));   // 8 x bf16 (bit pattern)
typedef float v4f __attribute__((ext_vector_type(4)));

__device__ __forceinline__ float bf2f(u16 u) {
    union { unsigned int i; float f; } v; v.i = ((unsigned int)u) << 16; return v.f;
}
__device__ __forceinline__ u16 f2bf(float f) {
    union { float f; unsigned int i; } v; v.f = f;
    unsigned int u = v.i;
    unsigned int r = u + 0x7fffu + ((u >> 16) & 1u);   // RNE
    return (u16)(r >> 16);
}

// async 16B global->LDS DMA: lane L's data lands at ldsbase + L*16
__device__ __forceinline__ void gload16(const u16* g, u16* l) {
    __builtin_amdgcn_global_load_lds(
        (const __attribute__((address_space(1))) void*)g,
        (__attribute__((address_space(3))) void*)l,
        16, 0, 0);
}

// ---------------------------------------------------------------------------
// Shared GEMM geometry (BK=64): LDS rows of 64 bf16 = 8 chunks of 16B.
// Physical chunk p of row r holds logical chunk p ^ (r&7) (conflict-free b128).
// Staging: thread t=64w+lane, instr i: row = i*32 + w*8 + (lane>>3),
//          phys chunk = lane&7, global col chunk = (lane&7) ^ (lane>>3).
//
// tile_1024: 128x128 tile x K=1024 NT product, bf16 out. If mirror!=0 (caller
// guarantees Xb==Yb symmetric product, tm!=tn), also writes the transposed
// tile C[tn..][tm..] = tile^T directly via a 2-pass 64x136 LDS transpose
// (reuses Xs/Ys space: needs Xs,Ys contiguous -> callers carve one array).
// ---------------------------------------------------------------------------
__device__ __forceinline__ void tile_1024(
    const u16* __restrict__ Xb, const u16* __restrict__ Yb,
    u16* __restrict__ Cd, int tm, int tn, u16* Xs, u16* Ys, int mirror)
{
    int t = threadIdx.x, lane = t & 63, w = t >> 6;
    int wm = (w & 1) << 6, wn = (w >> 1) << 6;
    int fr = lane & 15, q = lane >> 4, m7 = fr & 7;
    int subrow = lane >> 3, cch = (lane & 7) ^ subrow;

    const u16* xg[4]; const u16* yg[4]; u16* xl[4]; u16* yl[4];
    #pragma unroll
    for (int i = 0; i < 4; i++) {
        int r = i * 32 + w * 8 + subrow;
        xg[i] = Xb + (long)(tm + r) * 1024 + cch * 8;
        yg[i] = Yb + (long)(tn + r) * 1024 + cch * 8;
        xl[i] = Xs + (i * 32 + w * 8) * 64;
        yl[i] = Ys + (i * 32 + w * 8) * 64;
    }

    v4f acc[4][4];
    #pragma unroll
    for (int i = 0; i < 4; i++)
        #pragma unroll
        for (int j = 0; j < 4; j++) {
            acc[i][j][0] = 0.f; acc[i][j][1] = 0.f; acc[i][j][2] = 0.f; acc[i][j][3] = 0.f;
        }

    for (int k0 = 0; k0 < 1024; k0 += 64) {
        __syncthreads();
        #pragma unroll
        for (int i = 0; i < 4; i++) { gload16(xg[i] + k0, xl[i]); gload16(yg[i] + k0, yl[i]); }
        __syncthreads();
        v8s af[2][4], bfr[2][4];
        #pragma unroll
        for (int h = 0; h < 2; h++) {
            int ca = (((h << 2) + q) ^ m7) << 3;
            #pragma unroll
            for (int s = 0; s < 4; s++) {
                af[h][s]  = *(const v8s*)(Xs + (wm + s * 16 + fr) * 64 + ca);
                bfr[h][s] = *(const v8s*)(Ys + (wn + s * 16 + fr) * 64 + ca);
            }
        }
        #pragma unroll
        for (int h = 0; h < 2; h++)
            #pragma unroll
            for (int i = 0; i < 4; i++)
                #pragma unroll
                for (int j = 0; j < 4; j++)
                    acc[i][j] = __builtin_amdgcn_mfma_f32_16x16x32_bf16(af[h][i], bfr[h][j], acc[i][j], 0, 0, 0);
    }
    // primary tile write
    #pragma unroll
    for (int i = 0; i < 4; i++) {
        int rowb = tm + wm + i * 16 + q * 4;
        #pragma unroll
        for (int j = 0; j < 4; j++) {
            int col = tn + wn + j * 16 + fr;
            #pragma unroll
            for (int r = 0; r < 4; r++)
                Cd[(long)(rowb + r) * 1024 + col] = f2bf(acc[i][j][r]);
        }
    }
    if (mirror) {
        // transposed tile: C[tn+b][tm+a] = tile[a][b]; two passes of 64 rows
        u16* sm2 = Xs;                       // 64*136 u16 = 17408 B (spans Xs+Ys)
        #pragma unroll
        for (int p = 0; p < 2; p++) {
            __syncthreads();                 // protect Xs/Ys (p0) / prev pass (p1)
            if ((w & 1) == p) {              // waves holding rows [64p, 64p+64)
                #pragma unroll
                for (int i = 0; i < 4; i++)
                    #pragma unroll
                    for (int j = 0; j < 4; j++) {
                        int col = wn + j * 16 + fr;
                        #pragma unroll
                        for (int r = 0; r < 4; r++)
                            sm2[(i * 16 + q * 4 + r) * 136 + col] = f2bf(acc[i][j][r]);
                    }
            }
            __syncthreads();
            int rr = t >> 1, h2 = t & 1;     // out row rr, 32-col quarter h2
            #pragma unroll
            for (int v = 0; v < 4; v++) {
                uint4 ov; u16* po = (u16*)&ov;
                #pragma unroll
                for (int e = 0; e < 8; e++) po[e] = sm2[(h2 * 32 + v * 8 + e) * 136 + rr];
                *(uint4*)(Cd + (long)(tn + rr) * 1024 + tm + p * 64 + h2 * 32 + v * 8) = ov;
            }
        }
    }
}

// Single-K-iteration 128x128 tile (K=64, row stride 64). cf32 selects C dtype.
__device__ __forceinline__ void tile_k64(
    const u16* __restrict__ Xrows, const u16* __restrict__ Yrows,
    void* __restrict__ Cd, int crs, int cf32, u16* Xs, u16* Ys)
{
    int t = threadIdx.x, lane = t & 63, w = t >> 6;
    int wm = (w & 1) << 6, wn = (w >> 1) << 6;
    int fr = lane & 15, q = lane >> 4, m7 = fr & 7;
    int subrow = lane >> 3, cch = (lane & 7) ^ subrow;

    #pragma unroll
    for (int i = 0; i < 4; i++) {
        int r = i * 32 + w * 8 + subrow;
        gload16(Xrows + (long)r * 64 + cch * 8, Xs + (i * 32 + w * 8) * 64);
        gload16(Yrows + (long)r * 64 + cch * 8, Ys + (i * 32 + w * 8) * 64);
    }
    __syncthreads();

    v4f acc[4][4];
    #pragma unroll
    for (int i = 0; i < 4; i++)
        #pragma unroll
        for (int j = 0; j < 4; j++) {
            acc[i][j][0] = 0.f; acc[i][j][1] = 0.f; acc[i][j][2] = 0.f; acc[i][j][3] = 0.f;
        }
    v8s af[2][4], bfr[2][4];
    #pragma unroll
    for (int h = 0; h < 2; h++) {
        int ca = (((h << 2) + q) ^ m7) << 3;
        #pragma unroll
        for (int s = 0; s < 4; s++) {
            af[h][s]  = *(const v8s*)(Xs + (wm + s * 16 + fr) * 64 + ca);
            bfr[h][s] = *(const v8s*)(Ys + (wn + s * 16 + fr) * 64 + ca);
        }
    }
    #pragma unroll
    for (int h = 0; h < 2; h++)
        #pragma unroll
        for (int i = 0; i < 4; i++)
            #pragma unroll
            for (int j = 0; j < 4; j++)
                acc[i][j] = __builtin_amdgcn_mfma_f32_16x16x32_bf16(af[h][i], bfr[h][j], acc[i][j], 0, 0, 0);
    #pragma unroll
    for (int i = 0; i < 4; i++) {
        int rowb = wm + i * 16 + q * 4;
        #pragma unroll
        for (int j = 0; j < 4; j++) {
            int col = wn + j * 16 + fr;
            #pragma unroll
            for (int r = 0; r < 4; r++) {
                long o = (long)(rowb + r) * crs + col;
                if (cf32) ((float*)Cd)[o] = acc[i][j][r];
                else      ((u16*)Cd)[o] = f2bf(acc[i][j][r]);
            }
        }
    }
}

// 128x64 F@H^T tile over K-range [y*256,(y+1)*256). Fs:128x64, Hs:64x64 LDS.
__device__ __forceinline__ void hop_tile(
    const u16* __restrict__ Fb, const u16* __restrict__ Hb,
    int y, int tmt, float* __restrict__ Pd, u16* Fs, u16* Hs)
{
    int tm = tmt * 128, kb = y * 256;
    int t = threadIdx.x, lane = t & 63, w = t >> 6;
    int fr = lane & 15, q = lane >> 4, m7 = fr & 7;
    int subrow = lane >> 3, cch = (lane & 7) ^ subrow;

    const u16* fg[4]; u16* fl[4]; const u16* hg[2]; u16* hl[2];
    #pragma unroll
    for (int i = 0; i < 4; i++) {
        int r = i * 32 + w * 8 + subrow;
        fg[i] = Fb + (long)(tm + r) * 1024 + cch * 8;
        fl[i] = Fs + (i * 32 + w * 8) * 64;
    }
    #pragma unroll
    for (int i = 0; i < 2; i++) {
        int r = i * 32 + w * 8 + subrow;
        hg[i] = Hb + (long)r * 1024 + cch * 8;
        hl[i] = Hs + (i * 32 + w * 8) * 64;
    }

    v4f acc[2][4];
    #pragma unroll
    for (int i = 0; i < 2; i++)
        #pragma unroll
        for (int j = 0; j < 4; j++) {
            acc[i][j][0] = 0.f; acc[i][j][1] = 0.f; acc[i][j][2] = 0.f; acc[i][j][3] = 0.f;
        }

    for (int k0 = kb; k0 < kb + 256; k0 += 64) {
        __syncthreads();
        #pragma unroll
        for (int i = 0; i < 4; i++) gload16(fg[i] + k0, fl[i]);
        #pragma unroll
        for (int i = 0; i < 2; i++) gload16(hg[i] + k0, hl[i]);
        __syncthreads();
        v8s af[2][2], bfr[2][4];
        #pragma unroll
        for (int h = 0; h < 2; h++) {
            int ca = (((h << 2) + q) ^ m7) << 3;
            #pragma unroll
            for (int s = 0; s < 2; s++)
                af[h][s] = *(const v8s*)(Fs + (w * 32 + s * 16 + fr) * 64 + ca);
            #pragma unroll
            for (int s = 0; s < 4; s++)
                bfr[h][s] = *(const v8s*)(Hs + (s * 16 + fr) * 64 + ca);
        }
        #pragma unroll
        for (int h = 0; h < 2; h++)
            #pragma unroll
            for (int i = 0; i < 2; i++)
                #pragma unroll
                for (int j = 0; j < 4; j++)
                    acc[i][j] = __builtin_amdgcn_mfma_f32_16x16x32_bf16(af[h][i], bfr[h][j], acc[i][j], 0, 0, 0);
    }
    #pragma unroll
    for (int i = 0; i < 2; i++) {
        int rowb = tm + w * 32 + i * 16 + q * 4;
        #pragma unroll
        for (int j = 0; j < 4; j++) {
            int col = j * 16 + fr;
            #pragma unroll
            for (int r = 0; r < 4; r++)
                Pd[(long)(rowb + r) * 64 + col] = acc[i][j][r];
        }
    }
}

// fused prob_log/sigmoid/row-norm for one row (wave-collective, 64 lanes)
__device__ __forceinline__ void fused_row(
    const u16* __restrict__ r1, const u16* __restrict__ r2, const u16* __restrict__ r3,
    float w0, float w1, float w2, float b0, u16* __restrict__ Frow, int lane)
{
    float m1[16], m2[16], m3[16];
    float s1 = 0.f, s2 = 0.f, s3 = 0.f;
    #pragma unroll
    for (int c = 0; c < 16; c++) {
        int j = c * 64 + lane;
        m1[c] = bf2f(r1[j]); m2[c] = bf2f(r2[j]); m3[c] = bf2f(r3[j]);
        s1 += m1[c]; s2 += m2[c]; s3 += m3[c];
    }
    #pragma unroll
    for (int o = 1; o < 64; o <<= 1) {
        s1 += __shfl_xor(s1, o); s2 += __shfl_xor(s2, o); s3 += __shfl_xor(s3, o);
    }
    float i1 = 1.f / (s1 + 1e-6f), i2 = 1.f / (s2 + 1e-6f), i3 = 1.f / (s3 + 1e-6f);
    float sig[16];
    float ssum = 0.f;
    #pragma unroll
    for (int c = 0; c < 16; c++) {
        float p1 = fminf(fmaxf(m1[c] * i1, 1e-6f), 1.0f - 1e-6f);
        float p2 = fminf(fmaxf(m2[c] * i2, 1e-6f), 1.0f - 1e-6f);
        float p3 = fminf(fmaxf(m3[c] * i3, 1e-6f), 1.0f - 1e-6f);
        float l1 = __logf(p1 / (1.0f - p1 + 1e-6f));
        float l2 = __logf(p2 / (1.0f - p2 + 1e-6f));
        float l3 = __logf(p3 / (1.0f - p3 + 1e-6f));
        float lg = b0 + w0 * l1 + w1 * l2 + w2 * l3;
        float sg = 1.0f / (1.0f + __expf(-lg));
        sig[c] = sg; ssum += sg;
    }
    #pragma unroll
    for (int o = 1; o < 64; o <<= 1) ssum += __shfl_xor(ssum, o);
    float inv = 1.0f / (ssum + 1e-6f);
    #pragma unroll
    for (int c = 0; c < 16; c++) Frow[c * 64 + lane] = f2bf(sig[c] * inv);
}

// ---------------------------------------------------------------------------
// Generation-1: AAt (upper 36, direct-mirrored), AtA (same), A2 = A*A (full 64).
// 1D grid 1088 = 8 batches x 136 jobs, batch = blockIdx.x & 7 (XCD locality).
// ---------------------------------------------------------------------------
__global__ __launch_bounds__(256) void gemm_link1(
    const u16* __restrict__ A, const u16* __restrict__ AT,
    u16* __restrict__ AAt, u16* __restrict__ AtA, u16* __restrict__ A2)
{
    __shared__ __align__(16) u16 sm[16384];   // Xs | Ys contiguous (32 KB)
    u16* Xs = sm; u16* Ys = sm + 8192;
    const long SSq = (long)SS * SS;
    int b = blockIdx.x & 7;
    int job = blockIdx.x >> 3;
    const u16* Xb; const u16* Yb; u16* Cd;
    int ti, tj, mir;
    if (job < 72) {
        int tt = job < 36 ? job : job - 36;
        ti = 0;
        while (tt >= 8 - ti) { tt -= 8 - ti; ti++; }
        tj = ti + tt;
        mir = (ti != tj);
        if (job < 36) { Xb = A  + b * SSq; Yb = Xb; Cd = AAt + b * SSq; }
        else          { Xb = AT + b * SSq; Yb = Xb; Cd = AtA + b * SSq; }
    } else {
        int jj = job - 72;
        ti = jj >> 3; tj = jj & 7; mir = 0;
        Xb = A + b * SSq; Yb = AT + b * SSq; Cd = A2 + b * SSq;   // A2 = A*(AT)^T = A*A
    }
    tile_1024(Xb, Yb, Cd, ti * 128, tj * 128, Xs, Ys, mir);
}

// ---------------------------------------------------------------------------
// Gen-2 symmetric pair (576 blocks, direct-mirrored) + hop-0 GEMM tail
// (256 short MFMA blocks, split-K=4). Homogeneous MFMA work only.
// ---------------------------------------------------------------------------
__global__ __launch_bounds__(256) void gemm_link2h0(
    const u16* __restrict__ AAt, const u16* __restrict__ AtA,
    u16* __restrict__ AAt2, u16* __restrict__ AtA2,
    const u16* __restrict__ F0, const u16* __restrict__ hopVT,
    float* __restrict__ Pa, float* __restrict__ Pb)
{
    __shared__ __align__(16) u16 sm[16384];
    const long SSq = (long)SS * SS;
    int bx = blockIdx.x;
    if (bx < 576) {
        int z = bx & 15;
        int tt = bx >> 4, ti = 0;
        while (tt >= 8 - ti) { tt -= 8 - ti; ti++; }
        int tj = ti + tt;
        const u16* Xb = (z < 8 ? AAt : AtA) + (long)(z & 7) * SSq;
        u16* Cd = (z < 8 ? AAt2 : AtA2) + (long)(z & 7) * SSq;
        tile_1024(Xb, Xb, Cd, ti * 128, tj * 128, sm, sm + 8192, ti != tj);
    } else {
        int j = bx - 576;                  // 0..255
        int y = j >> 6, rest = j & 63;
        int tmt = rest >> 3, b = rest & 7;
        float* Pd = (y < 2 ? Pa + (long)y * 16 * 65536 : Pb + (long)(y - 2) * 16 * 65536)
                    + (long)b * 65536;                    // hop=0
        hop_tile(F0 + (long)b * SSq, hopVT + (long)b * 65536, y, tmt, Pd,
                 sm, sm + 8192);
    }
}

// hop-1 GEMM standalone, split-K=4: grid 256.
__global__ __launch_bounds__(256) void gemm_hop1(
    const u16* __restrict__ F1, const u16* __restrict__ hopVT,
    float* __restrict__ Pa, float* __restrict__ Pb)
{
    __shared__ u16 Fs[128 * 64];
    __shared__ u16 Hs[64 * 64];
    const long SSq = (long)SS * SS;
    int j = blockIdx.x;
    int y = j >> 6, rest = j & 63;
    int tmt = rest >> 3, b = rest & 7;
    float* Pd = (y < 2 ? Pa + (long)y * 16 * 65536 : Pb + (long)(y - 2) * 16 * 65536)
                + (long)(8 + b) * 65536;                  // hop=1
    hop_tile(F1 + (long)b * SSq, hopVT + (long)(8 + b) * 65536, y, tmt, Pd, Fs, Hs);
}

// ---------------------------------------------------------------------------
// Generic batched NT GEMM (projection + final): C[z] = X[z](MxK) * Y[z]^T(NxK)
// ---------------------------------------------------------------------------
__global__ __launch_bounds__(256) void gemm_nt(
    const u16* __restrict__ X, long sx,
    const u16* __restrict__ Y, long sy,
    void* __restrict__ Cv, long sc,
    int M, int N, int K, int cf32)
{
    __shared__ u16 Xs[128 * 64];
    __shared__ u16 Ys[128 * 64];
    const u16* Xb = X + (long)blockIdx.z * sx;
    const u16* Yb = Y + (long)blockIdx.z * sy;
    int tm = blockIdx.x * 128, tn = blockIdx.y * 128;
    int t = threadIdx.x, lane = t & 63, w = t >> 6;
    int wm = (w & 1) << 6, wn = (w >> 1) << 6;
    int fr = lane & 15, q = lane >> 4, m7 = fr & 7;
    int subrow = lane >> 3, cch = (lane & 7) ^ subrow;

    const u16* xg[4]; const u16* yg[4]; u16* xl[4]; u16* yl[4];
    #pragma unroll
    for (int i = 0; i < 4; i++) {
        int r = i * 32 + w * 8 + subrow;
        xg[i] = Xb + (long)(tm + r) * K + cch * 8;
        yg[i] = Yb + (long)(tn + r) * K + cch * 8;
        xl[i] = Xs + (i * 32 + w * 8) * 64;
        yl[i] = Ys + (i * 32 + w * 8) * 64;
    }

    v4f acc[4][4];
    #pragma unroll
    for (int i = 0; i < 4; i++)
        #pragma unroll
        for (int j = 0; j < 4; j++) {
            acc[i][j][0] = 0.f; acc[i][j][1] = 0.f; acc[i][j][2] = 0.f; acc[i][j][3] = 0.f;
        }

    for (int k0 = 0; k0 < K; k0 += 64) {
        __syncthreads();
        #pragma unroll
        for (int i = 0; i < 4; i++) { gload16(xg[i] + k0, xl[i]); gload16(yg[i] + k0, yl[i]); }
        __syncthreads();
        v8s af[2][4], bfr[2][4];
        #pragma unroll
        for (int h = 0; h < 2; h++) {
            int ca = (((h << 2) + q) ^ m7) << 3;
            #pragma unroll
            for (int s = 0; s < 4; s++) {
                af[h][s]  = *(const v8s*)(Xs + (wm + s * 16 + fr) * 64 + ca);
                bfr[h][s] = *(const v8s*)(Ys + (wn + s * 16 + fr) * 64 + ca);
            }
        }
        #pragma unroll
        for (int h = 0; h < 2; h++)
            #pragma unroll
            for (int i = 0; i < 4; i++)
                #pragma unroll
                for (int j = 0; j < 4; j++)
                    acc[i][j] = __builtin_amdgcn_mfma_f32_16x16x32_bf16(af[h][i], bfr[h][j], acc[i][j], 0, 0, 0);
    }
    long cb = (long)blockIdx.z * sc;
    #pragma unroll
    for (int i = 0; i < 4; i++) {
        int rowb = tm + wm + i * 16 + q * 4;
        #pragma unroll
        for (int j = 0; j < 4; j++) {
            int col = tn + wn + j * 16 + fr;
            #pragma unroll
            for (int r = 0; r < 4; r++) {
                long o = cb + (long)(rowb + r) * N + col;
                if (cf32) ((float*)Cv)[o] = acc[i][j][r];
                else      ((u16*)Cv)[o] = f2bf(acc[i][j][r]);
            }
        }
    }
}

// ---------------------------------------------------------------------------
// Merged: QK^T scores (512 blocks, fp32) + hopV projection (64 blocks, bf16)
// ---------------------------------------------------------------------------
__global__ __launch_bounds__(256) void k_qk_hopv(
    const u16* __restrict__ Qb, const u16* __restrict__ Kb,
    const u16* __restrict__ Vb, const u16* __restrict__ hopWb,
    float* __restrict__ scores, u16* __restrict__ hopvC)
{
    __shared__ u16 Xs[128 * 64];
    __shared__ u16 Ys[128 * 64];
    const long SSq = (long)SS * SS;
    const long SD = (long)SS * DD;
    int bx = blockIdx.x;
    if (bx < 512) {
        int z = bx & 7;
        int tt = bx >> 3;
        int tm = (tt >> 3) * 128, tn = (tt & 7) * 128;
        tile_k64(Qb + z * SD + (long)tm * 64, Kb + z * SD + (long)tn * 64,
                 scores + z * SSq + (long)tm * 1024 + tn, 1024, 1, Xs, Ys);
    } else {
        int tm = (bx - 512) * 128;
        tile_k64(Vb + (long)tm * 64, hopWb,
                 hopvC + (long)tm * 128, 128, 0, Xs, Ys);
    }
}

// ---------------------------------------------------------------------------
// Merged: softmax (2048 blocks) + hopVT transposes (256 blocks)
// ---------------------------------------------------------------------------
__global__ __launch_bounds__(256) void k_sm_hvt(
    const float* __restrict__ scores, const float* __restrict__ btab,
    const float* __restrict__ temp, u16* __restrict__ A,
    const u16* __restrict__ hopvC, u16* __restrict__ hopVT)
{
    __shared__ __align__(16) float smf[3969];   // 15876 B
    int bx = blockIdx.x;
    int t = threadIdx.x;
    if (bx < 2048) {
        for (int i = t; i < 3969; i += 256) smf[i] = btab[i];
        __syncthreads();
        int lane = t & 63, w = t >> 6;
        long row = (long)bx * 4 + w;
        int i = (int)(row & 1023);
        int ih = i >> 5, iw = i & 31;
        float inv_t = 1.0f / fmaxf(temp[0], 0.1f);
        const float* srow = scores + row * 1024;
        float sc[16];
        float m = -1e30f;
        #pragma unroll
        for (int c = 0; c < 16; c++) {
            int j = c * 64 + lane;
            int jh = j >> 5, jw = j & 31;
            float pb = smf[(ih - jh + 31) * 63 + (iw - jw + 31)];
            float s = (srow[j] * 0.125f + pb) * inv_t;
            sc[c] = s; m = fmaxf(m, s);
        }
        #pragma unroll
        for (int o = 1; o < 64; o <<= 1) m = fmaxf(m, __shfl_xor(m, o));
        float sum = 0.f;
        #pragma unroll
        for (int c = 0; c < 16; c++) { sc[c] = __expf(sc[c] - m); sum += sc[c]; }
        #pragma unroll
        for (int o = 1; o < 64; o <<= 1) sum += __shfl_xor(sum, o);
        float inv = 1.0f / sum;
        #pragma unroll
        for (int c = 0; c < 16; c++) A[row * 1024 + c * 64 + lane] = f2bf(sc[c] * inv);
    } else {
        u16* tile = (u16*)smf;                 // 64*72 u16 = 9216 B
        int ex = bx - 2048;                    // 0..255
        int hop = ex >> 7, rem = ex & 127;
        int z = rem & 7, i0 = (rem >> 3) * 64;
        const u16* s = hopvC + (long)z * (1024 * 128) + hop * 64;
        u16* d = hopVT + (long)(hop * 8 + z) * 65536;
        int r = t >> 2, c0 = (t & 3) << 4;
        #pragma unroll
        for (int p = 0; p < 2; p++) {
            int c = c0 + p * 8;
            uint4 v = *(const uint4*)(s + (long)(i0 + r) * 128 + c);
            *(uint4*)(&tile[r * 72 + c]) = v;
        }
        __syncthreads();
        #pragma unroll
        for (int p = 0; p < 2; p++) {
            uint4 ov; u16* po = (u16*)&ov;
            #pragma unroll
            for (int e = 0; e < 8; e++) po[e] = tile[(c0 + p * 8 + e) * 72 + r];
            *(uint4*)(d + (long)r * 1024 + i0 + c0 + p * 8) = ov;
        }
    }
}

// fused hop-0: 2048 blocks, 1 row/wave
__global__ __launch_bounds__(256) void k_fused0(
    const u16* __restrict__ A, const u16* __restrict__ AAt,
    const u16* __restrict__ AtA, const float* __restrict__ fw,
    const float* __restrict__ fbv, u16* __restrict__ F0)
{
    int lane = threadIdx.x & 63, w = threadIdx.x >> 6;
    float w0 = fw[0], w1 = fw[1], w2 = fw[2], b0 = fbv[0];
    long row = (long)blockIdx.x * 4 + w;
    fused_row(A + row * 1024, AAt + row * 1024, AtA + row * 1024,
              w0, w1, w2, b0, F0 + row * 1024, lane);
}

// fused hop-1: 2048 blocks, 1 row/wave
__global__ __launch_bounds__(256) void k_fused1(
    const u16* __restrict__ A2, const u16* __restrict__ AAt2,
    const u16* __restrict__ AtA2, const float* __restrict__ fw,
    const float* __restrict__ fbv, u16* __restrict__ F1)
{
    int lane = threadIdx.x & 63, w = threadIdx.x >> 6;
    float w0 = fw[3], w1 = fw[4], w2 = fw[5], b0 = fbv[1];
    long row = (long)blockIdx.x * 4 + w;
    fused_row(A2 + row * 1024, AAt2 + row * 1024, AtA2 + row * 1024,
              w0, w1, w2, b0, F1 + row * 1024, lane);
}

// pack x + weights to bf16 (merged)
__global__ __launch_bounds__(256) void k_pack(
    const float* __restrict__ x, const float* __restrict__ Wq,
    const float* __restrict__ Wk, const float* __restrict__ Wv,
    const float* __restrict__ gW, const float* __restrict__ hopW,
    const float* __restrict__ outW, u16* __restrict__ xb,
    u16* __restrict__ wpack, u16* __restrict__ hopWb, u16* __restrict__ outWb)
{
    int bx = blockIdx.x;
    if (bx < 4096) {
        long i = (long)bx * 256 + threadIdx.x;
        float4 v = ((const float4*)x)[i];
        ushort4 o;
        o.x = f2bf(v.x); o.y = f2bf(v.y); o.z = f2bf(v.z); o.w = f2bf(v.w);
        ((ushort4*)xb)[i] = o;
    } else {
        int idx = (bx - 4096) * 256 + threadIdx.x;
        if (idx < 131072) {
            int r = idx >> 9, c = idx & 511;
            float v = 0.f;
            if (r < 64)       v = Wq[r * 512 + c];
            else if (r < 128) v = Wk[(r - 64) * 512 + c];
            else if (r < 192) v = Wv[(r - 128) * 512 + c];
            else if (r < 194) v = gW[(r - 192) * 512 + c];
            wpack[idx] = f2bf(v);
        } else if (idx < 131072 + 8192) {
            int i = idx - 131072;
            hopWb[i] = f2bf(hopW[i]);
        } else if (idx < 131072 + 8192 + 32768) {
            int i = idx - 131072 - 8192;
            outWb[i] = f2bf(outW[i]);
        }
    }
}

// RoPE + gate softmax + Vb
__global__ __launch_bounds__(256) void k_rope(
    const float* __restrict__ QKVG, const float* __restrict__ gateb,
    u16* __restrict__ Qb, u16* __restrict__ Kb, u16* __restrict__ Vb,
    float* __restrict__ gate)
{
    int t = threadIdx.x, l = t & 63, w = t >> 6;
    long row = (long)blockIdx.x * 4 + w;
    int spos = (int)(row & (SS - 1));
    const float* base = QKVG + row * 256;
    float q = base[l], k = base[64 + l], v = base[128 + l];
    float qp = __shfl_xor(q, 32), kp = __shfl_xor(k, 32);
    float sgn = (l < 32) ? -1.f : 1.f;
    int f = l & 31;
    float ang = (float)spos * exp2f(-(float)f * (13.287712379549449f / 32.0f));
    float cs = cosf(ang), sn = sinf(ang);
    Qb[row * 64 + l] = f2bf(q * cs + sgn * qp * sn);
    Kb[row * 64 + l] = f2bf(k * cs + sgn * kp * sn);
    Vb[row * 64 + l] = f2bf(v);
    if (l < 2) {
        float g0 = base[192] + gateb[0], g1 = base[193] + gateb[1];
        float m = fmaxf(g0, g1);
        float e0 = __expf(g0 - m), e1 = __expf(g1 - m);
        gate[row * 2 + l] = ((l == 0) ? e0 : e1) / (e0 + e1);
    }
}

// generic bf16 transpose (A -> AT)
__global__ __launch_bounds__(256) void k_transpose(
    const u16* __restrict__ src, u16* __restrict__ dst,
    int srs, int drs, long sbs, long dbs)
{
    __shared__ u16 tile[64 * 72];
    const u16* s = src + (long)blockIdx.z * sbs;
    u16* d = dst + (long)blockIdx.z * dbs;
    int i0 = blockIdx.x * 64, j0 = blockIdx.y * 64;
    int t = threadIdx.x;
    int r = t >> 2, c0 = (t & 3) << 4;
    #pragma unroll
    for (int p = 0; p < 2; p++) {
        int c = c0 + p * 8;
        uint4 v = *(const uint4*)(s + (long)(i0 + r) * srs + j0 + c);
        *(uint4*)(&tile[r * 72 + c]) = v;
    }
    __syncthreads();
    #pragma unroll
    for (int p = 0; p < 2; p++) {
        uint4 ov;
        u16* po = (u16*)&ov;
        #pragma unroll
        for (int e = 0; e < 8; e++) po[e] = tile[(c0 + p * 8 + e) * 72 + r];
        *(uint4*)(d + (long)(j0 + r) * drs + i0 + c0 + p * 8) = ov;
    }
}

// sum split-K=4 partials, gate-combine -> comb bf16 [8192][64]
__global__ __launch_bounds__(256) void k_combine(
    const float* __restrict__ Pa, const float* __restrict__ Pb,
    const float* __restrict__ gate, u16* __restrict__ comb)
{
    long idx = (long)blockIdx.x * 256 + threadIdx.x;   // 8192*64
    long srow = idx >> 6;
    int b = (int)(srow >> 10);
    long o = (long)(srow & 1023) * 64 + (idx & 63);
    float h0 = Pa[(long)b * 65536 + o] + Pa[(long)(16 + b) * 65536 + o]
             + Pb[(long)b * 65536 + o] + Pb[(long)(16 + b) * 65536 + o];
    float h1 = Pa[(long)(8 + b) * 65536 + o] + Pa[(long)(24 + b) * 65536 + o]
             + Pb[(long)(8 + b) * 65536 + o] + Pb[(long)(24 + b) * 65536 + o];
    float g0 = gate[srow * 2], g1 = gate[srow * 2 + 1];
    comb[idx] = f2bf(h0 * g0 + h1 * g1);
}

// ---------------------------------------------------------------------------
extern "C" void kernel_launch(void* const* d_in, const int* in_sizes, int n_in,
                              void* d_out, int out_size, void* d_ws, size_t ws_size,
                              hipStream_t stream) {
    const float* x    = (const float*)d_in[0];
    const float* Wq   = (const float*)d_in[1];
    const float* Wk   = (const float*)d_in[2];
    const float* Wv   = (const float*)d_in[3];
    const float* btab = (const float*)d_in[4];
    const float* fw   = (const float*)d_in[5];
    const float* fbv  = (const float*)d_in[6];
    const float* hopW = (const float*)d_in[7];
    const float* gW   = (const float*)d_in[8];
    const float* gb   = (const float*)d_in[9];
    const float* outW = (const float*)d_in[10];
    const float* temp = (const float*)d_in[11];
    float* out = (float*)d_out;

    char* wsb = (char*)d_ws;
    size_t off = 0;
    auto take = [&](size_t n) { char* p = wsb + off; off += (n + 255) & ~(size_t)255; return p; };
    u16* Qb      = (u16*)take(8192L * 64 * 2);
    u16* Kb      = (u16*)take(8192L * 64 * 2);
    u16* Vb      = (u16*)take(8192L * 64 * 2);
    float* gate  = (float*)take(8192L * 2 * 4);
    u16* wpack   = (u16*)take(256L * 512 * 2);
    u16* hopWb   = (u16*)take(2L * 64 * 64 * 2);
    u16* outWb   = (u16*)take(512L * 64 * 2);
    u16* hopvC   = (u16*)take(8192L * 128 * 2);      // [s][hop*64+e]
    u16* hopVT   = (u16*)take(2L * 8 * 64 * 1024 * 2);
    float* Pa    = (float*)take(2L * 16 * 65536 * 4);     // split-K partials y=0,1
    u16* comb    = (u16*)take(8192L * 64 * 2);
    float* scoresF = (float*)take(8L * 1024 * 1024 * 4);  // 32 MB region
    float* QKVG  = (float*)scoresF;                   // alias: dead before scores
    u16* F0      = (u16*)scoresF;                     // alias: scores dead before F0
    u16* F1      = (u16*)scoresF + 8L * 1024 * 1024;  // second 16 MB of region
    u16* A       = (u16*)take(8L * 1024 * 1024 * 2);
    u16* xb      = (u16*)A;                           // alias: dead before A
    u16* AT      = (u16*)take(8L * 1024 * 1024 * 2);
    float* Pb    = (float*)AT;                        // alias: AT dead after link1
    u16* AAt     = (u16*)take(8L * 1024 * 1024 * 2);
    u16* AtA     = (u16*)take(8L * 1024 * 1024 * 2);
    u16* A2      = (u16*)take(8L * 1024 * 1024 * 2);
    u16* AAt2    = (u16*)take(8L * 1024 * 1024 * 2);
    u16* AtA2    = (u16*)take(8L * 1024 * 1024 * 2);
    (void)ws_size; (void)in_sizes; (void)n_in; (void)out_size;

    const long SSq = (long)SS * SS;

    // 1. pack inputs (merged)
    k_pack<<<4768, 256, 0, stream>>>(x, Wq, Wk, Wv, gW, hopW, outW, xb, wpack, hopWb, outWb);
    // 2. fused projection: QKVG[8192][256] = xb @ wpack^T (fp32)
    gemm_nt<<<dim3(64, 2, 1), 256, 0, stream>>>(xb, 0, wpack, 0, QKVG, 0, 8192, 256, 512, 1);
    // 3. rope + gate + Vb
    k_rope<<<2048, 256, 0, stream>>>(QKVG, gb, Qb, Kb, Vb, gate);
    // 4. scores = Q K^T (fp32) + hopvC = Vb @ hopWb^T (merged)
    k_qk_hopv<<<576, 256, 0, stream>>>(Qb, Kb, Vb, hopWb, scoresF, hopvC);
    // 5. softmax -> A + hopVT transposes (merged)
    k_sm_hvt<<<2304, 256, 0, stream>>>(scoresF, btab, temp, A, hopvC, hopVT);
    // 6. AT
    k_transpose<<<dim3(16, 16, 8), 256, 0, stream>>>(A, AT, 1024, 1024, SSq, SSq);
    // 7. generation-1: AAt, AtA (direct-mirrored) + A2 (full)
    gemm_link1<<<1088, 256, 0, stream>>>(A, AT, AAt, AtA, A2);
    // 8. fused hop-0 -> F0
    k_fused0<<<2048, 256, 0, stream>>>(A, AAt, AtA, fw, fbv, F0);
    // 9. gen-2 sym pair (direct-mirrored) + hop-0 GEMM tail
    gemm_link2h0<<<832, 256, 0, stream>>>(AAt, AtA, AAt2, AtA2, F0, hopVT, Pa, Pb);
    // 10. fused hop-1 -> F1
    k_fused1<<<2048, 256, 0, stream>>>(A2, AAt2, AtA2, fw, fbv, F1);
    // 11. hop-1 GEMM
    gemm_hop1<<<256, 256, 0, stream>>>(F1, hopVT, Pa, Pb);
    // 12. combine + output projection
    k_combine<<<2048, 256, 0, stream>>>(Pa, Pb, gate, comb);
    gemm_nt<<<dim3(64, 4, 1), 256, 0, stream>>>(comb, 0, outWb, 0, out, 0, 8192, 512, 64, 1);
}

// Round 9
// 327.251 us; speedup vs baseline: 1.0199x; 1.0199x over previous
//
#include <hip/hip_runtime.h>
#include <hip/hip_bf16.h>

// Problem constants
#define BB 8
#define SS 1024
#define HH 512
#define DD 64

typedef unsigned short u16;
typedef short v8s __attribute__((ext_vector_type(8)));   // 8 x bf16 (bit pattern)
typedef float v4f __attribute__((ext_vector_type(4)));

__device__ __forceinline__ float bf2f(u16 u) {
    union { unsigned int i; float f; } v; v.i = ((unsigned int)u) << 16; return v.f;
}
__device__ __forceinline__ u16 f2bf(float f) {
    union { float f; unsigned int i; } v; v.f = f;
    unsigned int u = v.i;
    unsigned int r = u + 0x7fffu + ((u >> 16) & 1u);   // RNE
    return (u16)(r >> 16);
}

// async 16B global->LDS DMA: lane L's data lands at ldsbase + L*16
__device__ __forceinline__ void gload16(const u16* g, u16* l) {
    __builtin_amdgcn_global_load_lds(
        (const __attribute__((address_space(1))) void*)g,
        (__attribute__((address_space(3))) void*)l,
        16, 0, 0);
}

// ---------------------------------------------------------------------------
// Shared GEMM geometry (BK=64): LDS rows of 64 bf16 = 8 chunks of 16B.
// Physical chunk p of row r holds logical chunk p ^ (r&7) (conflict-free b128).
// Staging: thread t=64w+lane, instr i: row = i*32 + w*8 + (lane>>3),
//          phys chunk = lane&7, global col chunk = (lane&7) ^ (lane>>3).
// ---------------------------------------------------------------------------

// Core 128x128 tile x K=1024 NT product, bf16 out.
__device__ __forceinline__ void tile_1024(
    const u16* __restrict__ Xb, const u16* __restrict__ Yb,
    u16* __restrict__ Cd, int tm, int tn, u16* Xs, u16* Ys)
{
    int t = threadIdx.x, lane = t & 63, w = t >> 6;
    int wm = (w & 1) << 6, wn = (w >> 1) << 6;
    int fr = lane & 15, q = lane >> 4, m7 = fr & 7;
    int subrow = lane >> 3, cch = (lane & 7) ^ subrow;

    const u16* xg[4]; const u16* yg[4]; u16* xl[4]; u16* yl[4];
    #pragma unroll
    for (int i = 0; i < 4; i++) {
        int r = i * 32 + w * 8 + subrow;
        xg[i] = Xb + (long)(tm + r) * 1024 + cch * 8;
        yg[i] = Yb + (long)(tn + r) * 1024 + cch * 8;
        xl[i] = Xs + (i * 32 + w * 8) * 64;
        yl[i] = Ys + (i * 32 + w * 8) * 64;
    }

    v4f acc[4][4];
    #pragma unroll
    for (int i = 0; i < 4; i++)
        #pragma unroll
        for (int j = 0; j < 4; j++) {
            acc[i][j][0] = 0.f; acc[i][j][1] = 0.f; acc[i][j][2] = 0.f; acc[i][j][3] = 0.f;
        }

    for (int k0 = 0; k0 < 1024; k0 += 64) {
        __syncthreads();
        #pragma unroll
        for (int i = 0; i < 4; i++) { gload16(xg[i] + k0, xl[i]); gload16(yg[i] + k0, yl[i]); }
        __syncthreads();
        v8s af[2][4], bfr[2][4];
        #pragma unroll
        for (int h = 0; h < 2; h++) {
            int ca = (((h << 2) + q) ^ m7) << 3;
            #pragma unroll
            for (int s = 0; s < 4; s++) {
                af[h][s]  = *(const v8s*)(Xs + (wm + s * 16 + fr) * 64 + ca);
                bfr[h][s] = *(const v8s*)(Ys + (wn + s * 16 + fr) * 64 + ca);
            }
        }
        #pragma unroll
        for (int h = 0; h < 2; h++)
            #pragma unroll
            for (int i = 0; i < 4; i++)
                #pragma unroll
                for (int j = 0; j < 4; j++)
                    acc[i][j] = __builtin_amdgcn_mfma_f32_16x16x32_bf16(af[h][i], bfr[h][j], acc[i][j], 0, 0, 0);
    }
    #pragma unroll
    for (int i = 0; i < 4; i++) {
        int rowb = tm + wm + i * 16 + q * 4;
        #pragma unroll
        for (int j = 0; j < 4; j++) {
            int col = tn + wn + j * 16 + fr;
            #pragma unroll
            for (int r = 0; r < 4; r++)
                Cd[(long)(rowb + r) * 1024 + col] = f2bf(acc[i][j][r]);
        }
    }
}

// Single-K-iteration 128x128 tile (K=64, row stride 64). cf32 selects C dtype.
__device__ __forceinline__ void tile_k64(
    const u16* __restrict__ Xrows, const u16* __restrict__ Yrows,
    void* __restrict__ Cd, int crs, int cf32, u16* Xs, u16* Ys)
{
    int t = threadIdx.x, lane = t & 63, w = t >> 6;
    int wm = (w & 1) << 6, wn = (w >> 1) << 6;
    int fr = lane & 15, q = lane >> 4, m7 = fr & 7;
    int subrow = lane >> 3, cch = (lane & 7) ^ subrow;

    #pragma unroll
    for (int i = 0; i < 4; i++) {
        int r = i * 32 + w * 8 + subrow;
        gload16(Xrows + (long)r * 64 + cch * 8, Xs + (i * 32 + w * 8) * 64);
        gload16(Yrows + (long)r * 64 + cch * 8, Ys + (i * 32 + w * 8) * 64);
    }
    __syncthreads();

    v4f acc[4][4];
    #pragma unroll
    for (int i = 0; i < 4; i++)
        #pragma unroll
        for (int j = 0; j < 4; j++) {
            acc[i][j][0] = 0.f; acc[i][j][1] = 0.f; acc[i][j][2] = 0.f; acc[i][j][3] = 0.f;
        }
    v8s af[2][4], bfr[2][4];
    #pragma unroll
    for (int h = 0; h < 2; h++) {
        int ca = (((h << 2) + q) ^ m7) << 3;
        #pragma unroll
        for (int s = 0; s < 4; s++) {
            af[h][s]  = *(const v8s*)(Xs + (wm + s * 16 + fr) * 64 + ca);
            bfr[h][s] = *(const v8s*)(Ys + (wn + s * 16 + fr) * 64 + ca);
        }
    }
    #pragma unroll
    for (int h = 0; h < 2; h++)
        #pragma unroll
        for (int i = 0; i < 4; i++)
            #pragma unroll
            for (int j = 0; j < 4; j++)
                acc[i][j] = __builtin_amdgcn_mfma_f32_16x16x32_bf16(af[h][i], bfr[h][j], acc[i][j], 0, 0, 0);
    #pragma unroll
    for (int i = 0; i < 4; i++) {
        int rowb = wm + i * 16 + q * 4;
        #pragma unroll
        for (int j = 0; j < 4; j++) {
            int col = wn + j * 16 + fr;
            #pragma unroll
            for (int r = 0; r < 4; r++) {
                long o = (long)(rowb + r) * crs + col;
                if (cf32) ((float*)Cd)[o] = acc[i][j][r];
                else      ((u16*)Cd)[o] = f2bf(acc[i][j][r]);
            }
        }
    }
}

// 128x64 F@H^T tile over K-range [y*256,(y+1)*256). Fs:128x64, Hs:64x64 LDS.
__device__ __forceinline__ void hop_tile(
    const u16* __restrict__ Fb, const u16* __restrict__ Hb,
    int y, int tmt, float* __restrict__ Pd, u16* Fs, u16* Hs)
{
    int tm = tmt * 128, kb = y * 256;
    int t = threadIdx.x, lane = t & 63, w = t >> 6;
    int fr = lane & 15, q = lane >> 4, m7 = fr & 7;
    int subrow = lane >> 3, cch = (lane & 7) ^ subrow;

    const u16* fg[4]; u16* fl[4]; const u16* hg[2]; u16* hl[2];
    #pragma unroll
    for (int i = 0; i < 4; i++) {
        int r = i * 32 + w * 8 + subrow;
        fg[i] = Fb + (long)(tm + r) * 1024 + cch * 8;
        fl[i] = Fs + (i * 32 + w * 8) * 64;
    }
    #pragma unroll
    for (int i = 0; i < 2; i++) {
        int r = i * 32 + w * 8 + subrow;
        hg[i] = Hb + (long)r * 1024 + cch * 8;
        hl[i] = Hs + (i * 32 + w * 8) * 64;
    }

    v4f acc[2][4];
    #pragma unroll
    for (int i = 0; i < 2; i++)
        #pragma unroll
        for (int j = 0; j < 4; j++) {
            acc[i][j][0] = 0.f; acc[i][j][1] = 0.f; acc[i][j][2] = 0.f; acc[i][j][3] = 0.f;
        }

    for (int k0 = kb; k0 < kb + 256; k0 += 64) {
        __syncthreads();
        #pragma unroll
        for (int i = 0; i < 4; i++) gload16(fg[i] + k0, fl[i]);
        #pragma unroll
        for (int i = 0; i < 2; i++) gload16(hg[i] + k0, hl[i]);
        __syncthreads();
        v8s af[2][2], bfr[2][4];
        #pragma unroll
        for (int h = 0; h < 2; h++) {
            int ca = (((h << 2) + q) ^ m7) << 3;
            #pragma unroll
            for (int s = 0; s < 2; s++)
                af[h][s] = *(const v8s*)(Fs + (w * 32 + s * 16 + fr) * 64 + ca);
            #pragma unroll
            for (int s = 0; s < 4; s++)
                bfr[h][s] = *(const v8s*)(Hs + (s * 16 + fr) * 64 + ca);
        }
        #pragma unroll
        for (int h = 0; h < 2; h++)
            #pragma unroll
            for (int i = 0; i < 2; i++)
                #pragma unroll
                for (int j = 0; j < 4; j++)
                    acc[i][j] = __builtin_amdgcn_mfma_f32_16x16x32_bf16(af[h][i], bfr[h][j], acc[i][j], 0, 0, 0);
    }
    #pragma unroll
    for (int i = 0; i < 2; i++) {
        int rowb = tm + w * 32 + i * 16 + q * 4;
        #pragma unroll
        for (int j = 0; j < 4; j++) {
            int col = j * 16 + fr;
            #pragma unroll
            for (int r = 0; r < 4; r++)
                Pd[(long)(rowb + r) * 64 + col] = acc[i][j][r];
        }
    }
}

// mirror one off-diagonal 128x128 tile: C[tj][ti] = C[ti][tj]^T. sm: 128*136 u16.
__device__ __forceinline__ void mirror_tile(u16* __restrict__ C, int ti, int tj, u16* sm)
{
    int t = threadIdx.x;
    int r = t >> 1, ch = (t & 1) << 6;
    const u16* src = C + (long)(ti * 128 + r) * 1024 + tj * 128 + ch;
    #pragma unroll
    for (int p = 0; p < 8; p++) {
        uint4 v = *(const uint4*)(src + p * 8);
        *(uint4*)(&sm[r * 136 + ch + p * 8]) = v;
    }
    __syncthreads();
    u16* dst = C + (long)(tj * 128 + r) * 1024 + ti * 128 + ch;
    #pragma unroll
    for (int p = 0; p < 8; p++) {
        uint4 ov; u16* po = (u16*)&ov;
        #pragma unroll
        for (int e = 0; e < 8; e++) po[e] = sm[(ch + p * 8 + e) * 136 + r];
        *(uint4*)(dst + p * 8) = ov;
    }
}

// fused prob_log/sigmoid/row-norm for one row (wave-collective, 64 lanes).
// Vectorized: lane handles 16 CONTIGUOUS columns [lane*16, lane*16+16).
__device__ __forceinline__ void fused_row(
    const u16* __restrict__ r1, const u16* __restrict__ r2, const u16* __restrict__ r3,
    float w0, float w1, float w2, float b0, u16* __restrict__ Frow, int lane)
{
    int base = lane << 4;
    union U { uint4 v; u16 s[8]; };
    U a[2], b[2], c[2];
    a[0].v = *(const uint4*)(r1 + base); a[1].v = *(const uint4*)(r1 + base + 8);
    b[0].v = *(const uint4*)(r2 + base); b[1].v = *(const uint4*)(r2 + base + 8);
    c[0].v = *(const uint4*)(r3 + base); c[1].v = *(const uint4*)(r3 + base + 8);
    float m1[16], m2[16], m3[16];
    float s1 = 0.f, s2 = 0.f, s3 = 0.f;
    #pragma unroll
    for (int h = 0; h < 2; h++)
        #pragma unroll
        for (int e = 0; e < 8; e++) {
            int k = h * 8 + e;
            m1[k] = bf2f(a[h].s[e]); m2[k] = bf2f(b[h].s[e]); m3[k] = bf2f(c[h].s[e]);
            s1 += m1[k]; s2 += m2[k]; s3 += m3[k];
        }
    #pragma unroll
    for (int o = 1; o < 64; o <<= 1) {
        s1 += __shfl_xor(s1, o); s2 += __shfl_xor(s2, o); s3 += __shfl_xor(s3, o);
    }
    float i1 = 1.f / (s1 + 1e-6f), i2 = 1.f / (s2 + 1e-6f), i3 = 1.f / (s3 + 1e-6f);
    float sig[16];
    float ssum = 0.f;
    #pragma unroll
    for (int k = 0; k < 16; k++) {
        float p1 = fminf(fmaxf(m1[k] * i1, 1e-6f), 1.0f - 1e-6f);
        float p2 = fminf(fmaxf(m2[k] * i2, 1e-6f), 1.0f - 1e-6f);
        float p3 = fminf(fmaxf(m3[k] * i3, 1e-6f), 1.0f - 1e-6f);
        float l1 = __logf(p1 / (1.0f - p1 + 1e-6f));
        float l2 = __logf(p2 / (1.0f - p2 + 1e-6f));
        float l3 = __logf(p3 / (1.0f - p3 + 1e-6f));
        float lg = b0 + w0 * l1 + w1 * l2 + w2 * l3;
        float sg = 1.0f / (1.0f + __expf(-lg));
        sig[k] = sg; ssum += sg;
    }
    #pragma unroll
    for (int o = 1; o < 64; o <<= 1) ssum += __shfl_xor(ssum, o);
    float inv = 1.0f / (ssum + 1e-6f);
    U o0, o1;
    #pragma unroll
    for (int e = 0; e < 8; e++) { o0.s[e] = f2bf(sig[e] * inv); o1.s[e] = f2bf(sig[8 + e] * inv); }
    *(uint4*)(Frow + base) = o0.v;
    *(uint4*)(Frow + base + 8) = o1.v;
}

// ---------------------------------------------------------------------------
// Generation-1: AAt (upper 36), AtA (upper 36), A2 = A*A (full 64).
// 1D grid 1088 = 8 batches x 136 jobs, batch = blockIdx.x & 7 (XCD locality).
// ---------------------------------------------------------------------------
__global__ __launch_bounds__(256) void gemm_link1(
    const u16* __restrict__ A, const u16* __restrict__ AT,
    u16* __restrict__ AAt, u16* __restrict__ AtA, u16* __restrict__ A2)
{
    __shared__ u16 Xs[128 * 64];
    __shared__ u16 Ys[128 * 64];
    const long SSq = (long)SS * SS;
    int b = blockIdx.x & 7;
    int job = blockIdx.x >> 3;
    const u16* Xb; const u16* Yb; u16* Cd;
    int ti, tj;
    if (job < 72) {
        int tt = job < 36 ? job : job - 36;
        ti = 0;
        while (tt >= 8 - ti) { tt -= 8 - ti; ti++; }
        tj = ti + tt;
        if (job < 36) { Xb = A  + b * SSq; Yb = Xb; Cd = AAt + b * SSq; }
        else          { Xb = AT + b * SSq; Yb = Xb; Cd = AtA + b * SSq; }
    } else {
        int jj = job - 72;
        ti = jj >> 3; tj = jj & 7;
        Xb = A + b * SSq; Yb = AT + b * SSq; Cd = A2 + b * SSq;   // A2 = A*(AT)^T = A*A
    }
    tile_1024(Xb, Yb, Cd, ti * 128, tj * 128, Xs, Ys);
}

// ---------------------------------------------------------------------------
// Gen-2 symmetric pair (576 blocks, upper tiles) + hop-0 GEMM tail
// (256 short MFMA blocks, split-K=4). Homogeneous MFMA work only.
// ---------------------------------------------------------------------------
__global__ __launch_bounds__(256) void gemm_link2h0(
    const u16* __restrict__ AAt, const u16* __restrict__ AtA,
    u16* __restrict__ AAt2, u16* __restrict__ AtA2,
    const u16* __restrict__ F0, const u16* __restrict__ hopVT,
    float* __restrict__ Pa, float* __restrict__ Pb)
{
    __shared__ u16 Xs[128 * 64];
    __shared__ u16 Ys[128 * 64];
    const long SSq = (long)SS * SS;
    int bx = blockIdx.x;
    if (bx < 576) {
        int z = bx & 15;
        int tt = bx >> 4, ti = 0;
        while (tt >= 8 - ti) { tt -= 8 - ti; ti++; }
        int tj = ti + tt;
        const u16* Xb = (z < 8 ? AAt : AtA) + (long)(z & 7) * SSq;
        u16* Cd = (z < 8 ? AAt2 : AtA2) + (long)(z & 7) * SSq;
        tile_1024(Xb, Xb, Cd, ti * 128, tj * 128, Xs, Ys);
    } else {
        int j = bx - 576;                  // 0..255
        int y = j >> 6, rest = j & 63;
        int tmt = rest >> 3, b = rest & 7;
        float* Pd = (y < 2 ? Pa + (long)y * 16 * 65536 : Pb + (long)(y - 2) * 16 * 65536)
                    + (long)b * 65536;                    // hop=0
        hop_tile(F0 + (long)b * SSq, hopVT + (long)b * 65536, y, tmt, Pd, Xs, Ys);
    }
}

// hop-1 GEMM standalone, split-K=4: grid 256.
__global__ __launch_bounds__(256) void gemm_hop1(
    const u16* __restrict__ F1, const u16* __restrict__ hopVT,
    float* __restrict__ Pa, float* __restrict__ Pb)
{
    __shared__ u16 Fs[128 * 64];
    __shared__ u16 Hs[64 * 64];
    const long SSq = (long)SS * SS;
    int j = blockIdx.x;
    int y = j >> 6, rest = j & 63;
    int tmt = rest >> 3, b = rest & 7;
    float* Pd = (y < 2 ? Pa + (long)y * 16 * 65536 : Pb + (long)(y - 2) * 16 * 65536)
                + (long)(8 + b) * 65536;                  // hop=1
    hop_tile(F1 + (long)b * SSq, hopVT + (long)(8 + b) * 65536, y, tmt, Pd, Fs, Hs);
}

// ---------------------------------------------------------------------------
// Generic batched NT GEMM (projection + final): C[z] = X[z](MxK) * Y[z]^T(NxK)
// ---------------------------------------------------------------------------
__global__ __launch_bounds__(256) void gemm_nt(
    const u16* __restrict__ X, long sx,
    const u16* __restrict__ Y, long sy,
    void* __restrict__ Cv, long sc,
    int M, int N, int K, int cf32)
{
    __shared__ u16 Xs[128 * 64];
    __shared__ u16 Ys[128 * 64];
    const u16* Xb = X + (long)blockIdx.z * sx;
    const u16* Yb = Y + (long)blockIdx.z * sy;
    int tm = blockIdx.x * 128, tn = blockIdx.y * 128;
    int t = threadIdx.x, lane = t & 63, w = t >> 6;
    int wm = (w & 1) << 6, wn = (w >> 1) << 6;
    int fr = lane & 15, q = lane >> 4, m7 = fr & 7;
    int subrow = lane >> 3, cch = (lane & 7) ^ subrow;

    const u16* xg[4]; const u16* yg[4]; u16* xl[4]; u16* yl[4];
    #pragma unroll
    for (int i = 0; i < 4; i++) {
        int r = i * 32 + w * 8 + subrow;
        xg[i] = Xb + (long)(tm + r) * K + cch * 8;
        yg[i] = Yb + (long)(tn + r) * K + cch * 8;
        xl[i] = Xs + (i * 32 + w * 8) * 64;
        yl[i] = Ys + (i * 32 + w * 8) * 64;
    }

    v4f acc[4][4];
    #pragma unroll
    for (int i = 0; i < 4; i++)
        #pragma unroll
        for (int j = 0; j < 4; j++) {
            acc[i][j][0] = 0.f; acc[i][j][1] = 0.f; acc[i][j][2] = 0.f; acc[i][j][3] = 0.f;
        }

    for (int k0 = 0; k0 < K; k0 += 64) {
        __syncthreads();
        #pragma unroll
        for (int i = 0; i < 4; i++) { gload16(xg[i] + k0, xl[i]); gload16(yg[i] + k0, yl[i]); }
        __syncthreads();
        v8s af[2][4], bfr[2][4];
        #pragma unroll
        for (int h = 0; h < 2; h++) {
            int ca = (((h << 2) + q) ^ m7) << 3;
            #pragma unroll
            for (int s = 0; s < 4; s++) {
                af[h][s]  = *(const v8s*)(Xs + (wm + s * 16 + fr) * 64 + ca);
                bfr[h][s] = *(const v8s*)(Ys + (wn + s * 16 + fr) * 64 + ca);
            }
        }
        #pragma unroll
        for (int h = 0; h < 2; h++)
            #pragma unroll
            for (int i = 0; i < 4; i++)
                #pragma unroll
                for (int j = 0; j < 4; j++)
                    acc[i][j] = __builtin_amdgcn_mfma_f32_16x16x32_bf16(af[h][i], bfr[h][j], acc[i][j], 0, 0, 0);
    }
    long cb = (long)blockIdx.z * sc;
    #pragma unroll
    for (int i = 0; i < 4; i++) {
        int rowb = tm + wm + i * 16 + q * 4;
        #pragma unroll
        for (int j = 0; j < 4; j++) {
            int col = tn + wn + j * 16 + fr;
            #pragma unroll
            for (int r = 0; r < 4; r++) {
                long o = cb + (long)(rowb + r) * N + col;
                if (cf32) ((float*)Cv)[o] = acc[i][j][r];
                else      ((u16*)Cv)[o] = f2bf(acc[i][j][r]);
            }
        }
    }
}

// ---------------------------------------------------------------------------
// Merged: QK^T scores (512 blocks, fp32) + hopV projection (64 blocks, bf16)
// ---------------------------------------------------------------------------
__global__ __launch_bounds__(256) void k_qk_hopv(
    const u16* __restrict__ Qb, const u16* __restrict__ Kb,
    const u16* __restrict__ Vb, const u16* __restrict__ hopWb,
    float* __restrict__ scores, u16* __restrict__ hopvC)
{
    __shared__ u16 Xs[128 * 64];
    __shared__ u16 Ys[128 * 64];
    const long SSq = (long)SS * SS;
    const long SD = (long)SS * DD;
    int bx = blockIdx.x;
    if (bx < 512) {
        int z = bx & 7;
        int tt = bx >> 3;
        int tm = (tt >> 3) * 128, tn = (tt & 7) * 128;
        tile_k64(Qb + z * SD + (long)tm * 64, Kb + z * SD + (long)tn * 64,
                 scores + z * SSq + (long)tm * 1024 + tn, 1024, 1, Xs, Ys);
    } else {
        int tm = (bx - 512) * 128;
        tile_k64(Vb + (long)tm * 64, hopWb,
                 hopvC + (long)tm * 128, 128, 0, Xs, Ys);
    }
}

// ---------------------------------------------------------------------------
// Merged: softmax (2048 blocks) + hopVT transposes (256 blocks)
// ---------------------------------------------------------------------------
__global__ __launch_bounds__(256) void k_sm_hvt(
    const float* __restrict__ scores, const float* __restrict__ btab,
    const float* __restrict__ temp, u16* __restrict__ A,
    const u16* __restrict__ hopvC, u16* __restrict__ hopVT)
{
    __shared__ __align__(16) float smf[3969];   // 15876 B
    int bx = blockIdx.x;
    int t = threadIdx.x;
    if (bx < 2048) {
        for (int i = t; i < 3969; i += 256) smf[i] = btab[i];
        __syncthreads();
        int lane = t & 63, w = t >> 6;
        long row = (long)bx * 4 + w;
        int i = (int)(row & 1023);
        int ih = i >> 5, iw = i & 31;
        float inv_t = 1.0f / fmaxf(temp[0], 0.1f);
        const float* srow = scores + row * 1024;
        float sc[16];
        float m = -1e30f;
        #pragma unroll
        for (int c = 0; c < 16; c++) {
            int j = c * 64 + lane;
            int jh = j >> 5, jw = j & 31;
            float pb = smf[(ih - jh + 31) * 63 + (iw - jw + 31)];
            float s = (srow[j] * 0.125f + pb) * inv_t;
            sc[c] = s; m = fmaxf(m, s);
        }
        #pragma unroll
        for (int o = 1; o < 64; o <<= 1) m = fmaxf(m, __shfl_xor(m, o));
        float sum = 0.f;
        #pragma unroll
        for (int c = 0; c < 16; c++) { sc[c] = __expf(sc[c] - m); sum += sc[c]; }
        #pragma unroll
        for (int o = 1; o < 64; o <<= 1) sum += __shfl_xor(sum, o);
        float inv = 1.0f / sum;
        #pragma unroll
        for (int c = 0; c < 16; c++) A[row * 1024 + c * 64 + lane] = f2bf(sc[c] * inv);
    } else {
        u16* tile = (u16*)smf;                 // 64*72 u16 = 9216 B
        int ex = bx - 2048;                    // 0..255
        int hop = ex >> 7, rem = ex & 127;
        int z = rem & 7, i0 = (rem >> 3) * 64;
        const u16* s = hopvC + (long)z * (1024 * 128) + hop * 64;
        u16* d = hopVT + (long)(hop * 8 + z) * 65536;
        int r = t >> 2, c0 = (t & 3) << 4;
        #pragma unroll
        for (int p = 0; p < 2; p++) {
            int c = c0 + p * 8;
            uint4 v = *(const uint4*)(s + (long)(i0 + r) * 128 + c);
            *(uint4*)(&tile[r * 72 + c]) = v;
        }
        __syncthreads();
        #pragma unroll
        for (int p = 0; p < 2; p++) {
            uint4 ov; u16* po = (u16*)&ov;
            #pragma unroll
            for (int e = 0; e < 8; e++) po[e] = tile[(c0 + p * 8 + e) * 72 + r];
            *(uint4*)(d + (long)r * 1024 + i0 + c0 + p * 8) = ov;
        }
    }
}

// mirror: 28 off-diag tiles x 16 matrices
__global__ __launch_bounds__(256) void k_mirror(u16* __restrict__ C0, u16* __restrict__ C1)
{
    __shared__ __align__(16) u16 sm[128 * 136];
    const long SSq = (long)SS * SS;
    int z = blockIdx.z;
    u16* C = (z < 8 ? C0 : C1) + (long)(z & 7) * SSq;
    int tt = blockIdx.x, ti = 0;
    while (tt >= 7 - ti) { tt -= 7 - ti; ti++; }
    int tj = ti + 1 + tt;
    mirror_tile(C, ti, tj, sm);
}

// fused hop-0: 2048 blocks, 1 row/wave
__global__ __launch_bounds__(256) void k_fused0(
    const u16* __restrict__ A, const u16* __restrict__ AAt,
    const u16* __restrict__ AtA, const float* __restrict__ fw,
    const float* __restrict__ fbv, u16* __restrict__ F0)
{
    int lane = threadIdx.x & 63, w = threadIdx.x >> 6;
    float w0 = fw[0], w1 = fw[1], w2 = fw[2], b0 = fbv[0];
    long row = (long)blockIdx.x * 4 + w;
    fused_row(A + row * 1024, AAt + row * 1024, AtA + row * 1024,
              w0, w1, w2, b0, F0 + row * 1024, lane);
}

// fused hop-1: 2048 blocks, 1 row/wave
__global__ __launch_bounds__(256) void k_fused1(
    const u16* __restrict__ A2, const u16* __restrict__ AAt2,
    const u16* __restrict__ AtA2, const float* __restrict__ fw,
    const float* __restrict__ fbv, u16* __restrict__ F1)
{
    int lane = threadIdx.x & 63, w = threadIdx.x >> 6;
    float w0 = fw[3], w1 = fw[4], w2 = fw[5], b0 = fbv[1];
    long row = (long)blockIdx.x * 4 + w;
    fused_row(A2 + row * 1024, AAt2 + row * 1024, AtA2 + row * 1024,
              w0, w1, w2, b0, F1 + row * 1024, lane);
}

// pack x + weights to bf16 (merged)
__global__ __launch_bounds__(256) void k_pack(
    const float* __restrict__ x, const float* __restrict__ Wq,
    const float* __restrict__ Wk, const float* __restrict__ Wv,
    const float* __restrict__ gW, const float* __restrict__ hopW,
    const float* __restrict__ outW, u16* __restrict__ xb,
    u16* __restrict__ wpack, u16* __restrict__ hopWb, u16* __restrict__ outWb)
{
    int bx = blockIdx.x;
    if (bx < 4096) {
        long i = (long)bx * 256 + threadIdx.x;
        float4 v = ((const float4*)x)[i];
        ushort4 o;
        o.x = f2bf(v.x); o.y = f2bf(v.y); o.z = f2bf(v.z); o.w = f2bf(v.w);
        ((ushort4*)xb)[i] = o;
    } else {
        int idx = (bx - 4096) * 256 + threadIdx.x;
        if (idx < 131072) {
            int r = idx >> 9, c = idx & 511;
            float v = 0.f;
            if (r < 64)       v = Wq[r * 512 + c];
            else if (r < 128) v = Wk[(r - 64) * 512 + c];
            else if (r < 192) v = Wv[(r - 128) * 512 + c];
            else if (r < 194) v = gW[(r - 192) * 512 + c];
            wpack[idx] = f2bf(v);
        } else if (idx < 131072 + 8192) {
            int i = idx - 131072;
            hopWb[i] = f2bf(hopW[i]);
        } else if (idx < 131072 + 8192 + 32768) {
            int i = idx - 131072 - 8192;
            outWb[i] = f2bf(outW[i]);
        }
    }
}

// RoPE + gate softmax + Vb
__global__ __launch_bounds__(256) void k_rope(
    const float* __restrict__ QKVG, const float* __restrict__ gateb,
    u16* __restrict__ Qb, u16* __restrict__ Kb, u16* __restrict__ Vb,
    float* __restrict__ gate)
{
    int t = threadIdx.x, l = t & 63, w = t >> 6;
    long row = (long)blockIdx.x * 4 + w;
    int spos = (int)(row & (SS - 1));
    const float* base = QKVG + row * 256;
    float q = base[l], k = base[64 + l], v = base[128 + l];
    float qp = __shfl_xor(q, 32), kp = __shfl_xor(k, 32);
    float sgn = (l < 32) ? -1.f : 1.f;
    int f = l & 31;
    float ang = (float)spos * exp2f(-(float)f * (13.287712379549449f / 32.0f));
    float cs = cosf(ang), sn = sinf(ang);
    Qb[row * 64 + l] = f2bf(q * cs + sgn * qp * sn);
    Kb[row * 64 + l] = f2bf(k * cs + sgn * kp * sn);
    Vb[row * 64 + l] = f2bf(v);
    if (l < 2) {
        float g0 = base[192] + gateb[0], g1 = base[193] + gateb[1];
        float m = fmaxf(g0, g1);
        float e0 = __expf(g0 - m), e1 = __expf(g1 - m);
        gate[row * 2 + l] = ((l == 0) ? e0 : e1) / (e0 + e1);
    }
}

// generic bf16 transpose (A -> AT)
__global__ __launch_bounds__(256) void k_transpose(
    const u16* __restrict__ src, u16* __restrict__ dst,
    int srs, int drs, long sbs, long dbs)
{
    __shared__ u16 tile[64 * 72];
    const u16* s = src + (long)blockIdx.z * sbs;
    u16* d = dst + (long)blockIdx.z * dbs;
    int i0 = blockIdx.x * 64, j0 = blockIdx.y * 64;
    int t = threadIdx.x;
    int r = t >> 2, c0 = (t & 3) << 4;
    #pragma unroll
    for (int p = 0; p < 2; p++) {
        int c = c0 + p * 8;
        uint4 v = *(const uint4*)(s + (long)(i0 + r) * srs + j0 + c);
        *(uint4*)(&tile[r * 72 + c]) = v;
    }
    __syncthreads();
    #pragma unroll
    for (int p = 0; p < 2; p++) {
        uint4 ov;
        u16* po = (u16*)&ov;
        #pragma unroll
        for (int e = 0; e < 8; e++) po[e] = tile[(c0 + p * 8 + e) * 72 + r];
        *(uint4*)(d + (long)(j0 + r) * drs + i0 + c0 + p * 8) = ov;
    }
}

// sum split-K=4 partials, gate-combine -> comb bf16 [8192][64]
__global__ __launch_bounds__(256) void k_combine(
    const float* __restrict__ Pa, const float* __restrict__ Pb,
    const float* __restrict__ gate, u16* __restrict__ comb)
{
    long idx = (long)blockIdx.x * 256 + threadIdx.x;   // 8192*64
    long srow = idx >> 6;
    int b = (int)(srow >> 10);
    long o = (long)(srow & 1023) * 64 + (idx & 63);
    float h0 = Pa[(long)b * 65536 + o] + Pa[(long)(16 + b) * 65536 + o]
             + Pb[(long)b * 65536 + o] + Pb[(long)(16 + b) * 65536 + o];
    float h1 = Pa[(long)(8 + b) * 65536 + o] + Pa[(long)(24 + b) * 65536 + o]
             + Pb[(long)(8 + b) * 65536 + o] + Pb[(long)(24 + b) * 65536 + o];
    float g0 = gate[srow * 2], g1 = gate[srow * 2 + 1];
    comb[idx] = f2bf(h0 * g0 + h1 * g1);
}

// ---------------------------------------------------------------------------
extern "C" void kernel_launch(void* const* d_in, const int* in_sizes, int n_in,
                              void* d_out, int out_size, void* d_ws, size_t ws_size,
                              hipStream_t stream) {
    const float* x    = (const float*)d_in[0];
    const float* Wq   = (const float*)d_in[1];
    const float* Wk   = (const float*)d_in[2];
    const float* Wv   = (const float*)d_in[3];
    const float* btab = (const float*)d_in[4];
    const float* fw   = (const float*)d_in[5];
    const float* fbv  = (const float*)d_in[6];
    const float* hopW = (const float*)d_in[7];
    const float* gW   = (const float*)d_in[8];
    const float* gb   = (const float*)d_in[9];
    const float* outW = (const float*)d_in[10];
    const float* temp = (const float*)d_in[11];
    float* out = (float*)d_out;

    char* wsb = (char*)d_ws;
    size_t off = 0;
    auto take = [&](size_t n) { char* p = wsb + off; off += (n + 255) & ~(size_t)255; return p; };
    u16* Qb      = (u16*)take(8192L * 64 * 2);
    u16* Kb      = (u16*)take(8192L * 64 * 2);
    u16* Vb      = (u16*)take(8192L * 64 * 2);
    float* gate  = (float*)take(8192L * 2 * 4);
    u16* wpack   = (u16*)take(256L * 512 * 2);
    u16* hopWb   = (u16*)take(2L * 64 * 64 * 2);
    u16* outWb   = (u16*)take(512L * 64 * 2);
    u16* hopvC   = (u16*)take(8192L * 128 * 2);      // [s][hop*64+e]
    u16* hopVT   = (u16*)take(2L * 8 * 64 * 1024 * 2);
    float* Pa    = (float*)take(2L * 16 * 65536 * 4);     // split-K partials y=0,1
    u16* comb    = (u16*)take(8192L * 64 * 2);
    float* scoresF = (float*)take(8L * 1024 * 1024 * 4);  // 32 MB region
    float* QKVG  = (float*)scoresF;                   // alias: dead before scores
    u16* F0      = (u16*)scoresF;                     // alias: scores dead before F0
    u16* F1      = (u16*)scoresF + 8L * 1024 * 1024;  // second 16 MB of region
    u16* A       = (u16*)take(8L * 1024 * 1024 * 2);
    u16* xb      = (u16*)A;                           // alias: dead before A
    u16* AT      = (u16*)take(8L * 1024 * 1024 * 2);
    float* Pb    = (float*)AT;                        // alias: AT dead after link1
    u16* AAt     = (u16*)take(8L * 1024 * 1024 * 2);
    u16* AtA     = (u16*)take(8L * 1024 * 1024 * 2);
    u16* A2      = (u16*)take(8L * 1024 * 1024 * 2);
    u16* AAt2    = (u16*)take(8L * 1024 * 1024 * 2);
    u16* AtA2    = (u16*)take(8L * 1024 * 1024 * 2);
    (void)ws_size; (void)in_sizes; (void)n_in; (void)out_size;

    const long SSq = (long)SS * SS;

    // 1. pack inputs (merged)
    k_pack<<<4768, 256, 0, stream>>>(x, Wq, Wk, Wv, gW, hopW, outW, xb, wpack, hopWb, outWb);
    // 2. fused projection: QKVG[8192][256] = xb @ wpack^T (fp32)
    gemm_nt<<<dim3(64, 2, 1), 256, 0, stream>>>(xb, 0, wpack, 0, QKVG, 0, 8192, 256, 512, 1);
    // 3. rope + gate + Vb
    k_rope<<<2048, 256, 0, stream>>>(QKVG, gb, Qb, Kb, Vb, gate);
    // 4. scores = Q K^T (fp32) + hopvC = Vb @ hopWb^T (merged)
    k_qk_hopv<<<576, 256, 0, stream>>>(Qb, Kb, Vb, hopWb, scoresF, hopvC);
    // 5. softmax -> A + hopVT transposes (merged)
    k_sm_hvt<<<2304, 256, 0, stream>>>(scoresF, btab, temp, A, hopvC, hopVT);
    // 6. AT
    k_transpose<<<dim3(16, 16, 8), 256, 0, stream>>>(A, AT, 1024, 1024, SSq, SSq);
    // 7. generation-1: AAt, AtA (upper) + A2 (full), then mirror
    gemm_link1<<<1088, 256, 0, stream>>>(A, AT, AAt, AtA, A2);
    k_mirror<<<dim3(28, 1, 16), 256, 0, stream>>>(AAt, AtA);
    // 8. fused hop-0 -> F0
    k_fused0<<<2048, 256, 0, stream>>>(A, AAt, AtA, fw, fbv, F0);
    // 9. gen-2 sym pair (upper) + hop-0 GEMM tail, then mirror
    gemm_link2h0<<<832, 256, 0, stream>>>(AAt, AtA, AAt2, AtA2, F0, hopVT, Pa, Pb);
    k_mirror<<<dim3(28, 1, 16), 256, 0, stream>>>(AAt2, AtA2);
    // 10. fused hop-1 -> F1
    k_fused1<<<2048, 256, 0, stream>>>(A2, AAt2, AtA2, fw, fbv, F1);
    // 11. hop-1 GEMM
    gemm_hop1<<<256, 256, 0, stream>>>(F1, hopVT, Pa, Pb);
    // 12. combine + output projection
    k_combine<<<2048, 256, 0, stream>>>(Pa, Pb, gate, comb);
    gemm_nt<<<dim3(64, 4, 1), 256, 0, stream>>>(comb, 0, outWb, 0, out, 0, 8192, 512, 64, 1);
}

// Round 10
// 305.357 us; speedup vs baseline: 1.0931x; 1.0717x over previous
//
#include <hip/hip_runtime.h>
#include <hip/hip_bf16.h>

// Problem constants
#define BB 8
#define SS 1024
#define HH 512
#define DD 64

typedef unsigned short u16;
typedef short v8s __attribute__((ext_vector_type(8)));   // 8 x bf16 (bit pattern)
typedef float v4f __attribute__((ext_vector_type(4)));

__device__ __forceinline__ float bf2f(u16 u) {
    union { unsigned int i; float f; } v; v.i = ((unsigned int)u) << 16; return v.f;
}
__device__ __forceinline__ u16 f2bf(float f) {
    union { float f; unsigned int i; } v; v.f = f;
    unsigned int u = v.i;
    unsigned int r = u + 0x7fffu + ((u >> 16) & 1u);   // RNE
    return (u16)(r >> 16);
}

// async 16B global->LDS DMA: lane L's data lands at ldsbase + L*16
__device__ __forceinline__ void gload16(const u16* g, u16* l) {
    __builtin_amdgcn_global_load_lds(
        (const __attribute__((address_space(1))) void*)g,
        (__attribute__((address_space(3))) void*)l,
        16, 0, 0);
}

// ---------------------------------------------------------------------------
// Shared GEMM geometry (BK=64): LDS rows of 64 bf16 = 8 chunks of 16B.
// Physical chunk p of row r holds logical chunk p ^ (r&7) (conflict-free b128).
// Staging: thread t=64w+lane, instr i: row = i*32 + w*8 + (lane>>3),
//          phys chunk = lane&7, global col chunk = (lane&7) ^ (lane>>3).
//
// tile_1024: 128x128 tile x K=1024 NT product, bf16 out. mirror!=0 (symmetric
// product, off-diagonal tile): ALSO writes C[tn..][tm..] = tile^T directly
// from registers — C-layout gives each lane 4 consecutive rows of one column,
// i.e. 4 consecutive u16 of the transposed tile -> one packed 8B store.
// No LDS, no barriers (round-8's LDS-transpose version regressed; this won't).
// ---------------------------------------------------------------------------
__device__ __forceinline__ void tile_1024(
    const u16* __restrict__ Xb, const u16* __restrict__ Yb,
    u16* __restrict__ Cd, int tm, int tn, u16* Xs, u16* Ys, int mirror)
{
    int t = threadIdx.x, lane = t & 63, w = t >> 6;
    int wm = (w & 1) << 6, wn = (w >> 1) << 6;
    int fr = lane & 15, q = lane >> 4, m7 = fr & 7;
    int subrow = lane >> 3, cch = (lane & 7) ^ subrow;

    const u16* xg[4]; const u16* yg[4]; u16* xl[4]; u16* yl[4];
    #pragma unroll
    for (int i = 0; i < 4; i++) {
        int r = i * 32 + w * 8 + subrow;
        xg[i] = Xb + (long)(tm + r) * 1024 + cch * 8;
        yg[i] = Yb + (long)(tn + r) * 1024 + cch * 8;
        xl[i] = Xs + (i * 32 + w * 8) * 64;
        yl[i] = Ys + (i * 32 + w * 8) * 64;
    }

    v4f acc[4][4];
    #pragma unroll
    for (int i = 0; i < 4; i++)
        #pragma unroll
        for (int j = 0; j < 4; j++) {
            acc[i][j][0] = 0.f; acc[i][j][1] = 0.f; acc[i][j][2] = 0.f; acc[i][j][3] = 0.f;
        }

    for (int k0 = 0; k0 < 1024; k0 += 64) {
        __syncthreads();
        #pragma unroll
        for (int i = 0; i < 4; i++) { gload16(xg[i] + k0, xl[i]); gload16(yg[i] + k0, yl[i]); }
        __syncthreads();
        v8s af[2][4], bfr[2][4];
        #pragma unroll
        for (int h = 0; h < 2; h++) {
            int ca = (((h << 2) + q) ^ m7) << 3;
            #pragma unroll
            for (int s = 0; s < 4; s++) {
                af[h][s]  = *(const v8s*)(Xs + (wm + s * 16 + fr) * 64 + ca);
                bfr[h][s] = *(const v8s*)(Ys + (wn + s * 16 + fr) * 64 + ca);
            }
        }
        #pragma unroll
        for (int h = 0; h < 2; h++)
            #pragma unroll
            for (int i = 0; i < 4; i++)
                #pragma unroll
                for (int j = 0; j < 4; j++)
                    acc[i][j] = __builtin_amdgcn_mfma_f32_16x16x32_bf16(af[h][i], bfr[h][j], acc[i][j], 0, 0, 0);
    }
    #pragma unroll
    for (int i = 0; i < 4; i++) {
        int rowb = tm + wm + i * 16 + q * 4;
        #pragma unroll
        for (int j = 0; j < 4; j++) {
            int col = tn + wn + j * 16 + fr;
            ushort4 pv;
            pv.x = f2bf(acc[i][j][0]); pv.y = f2bf(acc[i][j][1]);
            pv.z = f2bf(acc[i][j][2]); pv.w = f2bf(acc[i][j][3]);
            #pragma unroll
            for (int r = 0; r < 4; r++)
                Cd[(long)(rowb + r) * 1024 + col] = ((u16*)&pv)[r];
            if (mirror)   // transposed tile: 4 consecutive u16 at row=col
                *(ushort4*)(Cd + (long)col * 1024 + rowb) = pv;
        }
    }
}

// Single-K-iteration 128x128 tile (K=64, row stride 64). cf32 selects C dtype.
__device__ __forceinline__ void tile_k64(
    const u16* __restrict__ Xrows, const u16* __restrict__ Yrows,
    void* __restrict__ Cd, int crs, int cf32, u16* Xs, u16* Ys)
{
    int t = threadIdx.x, lane = t & 63, w = t >> 6;
    int wm = (w & 1) << 6, wn = (w >> 1) << 6;
    int fr = lane & 15, q = lane >> 4, m7 = fr & 7;
    int subrow = lane >> 3, cch = (lane & 7) ^ subrow;

    #pragma unroll
    for (int i = 0; i < 4; i++) {
        int r = i * 32 + w * 8 + subrow;
        gload16(Xrows + (long)r * 64 + cch * 8, Xs + (i * 32 + w * 8) * 64);
        gload16(Yrows + (long)r * 64 + cch * 8, Ys + (i * 32 + w * 8) * 64);
    }
    __syncthreads();

    v4f acc[4][4];
    #pragma unroll
    for (int i = 0; i < 4; i++)
        #pragma unroll
        for (int j = 0; j < 4; j++) {
            acc[i][j][0] = 0.f; acc[i][j][1] = 0.f; acc[i][j][2] = 0.f; acc[i][j][3] = 0.f;
        }
    v8s af[2][4], bfr[2][4];
    #pragma unroll
    for (int h = 0; h < 2; h++) {
        int ca = (((h << 2) + q) ^ m7) << 3;
        #pragma unroll
        for (int s = 0; s < 4; s++) {
            af[h][s]  = *(const v8s*)(Xs + (wm + s * 16 + fr) * 64 + ca);
            bfr[h][s] = *(const v8s*)(Ys + (wn + s * 16 + fr) * 64 + ca);
        }
    }
    #pragma unroll
    for (int h = 0; h < 2; h++)
        #pragma unroll
        for (int i = 0; i < 4; i++)
            #pragma unroll
            for (int j = 0; j < 4; j++)
                acc[i][j] = __builtin_amdgcn_mfma_f32_16x16x32_bf16(af[h][i], bfr[h][j], acc[i][j], 0, 0, 0);
    #pragma unroll
    for (int i = 0; i < 4; i++) {
        int rowb = wm + i * 16 + q * 4;
        #pragma unroll
        for (int j = 0; j < 4; j++) {
            int col = wn + j * 16 + fr;
            #pragma unroll
            for (int r = 0; r < 4; r++) {
                long o = (long)(rowb + r) * crs + col;
                if (cf32) ((float*)Cd)[o] = acc[i][j][r];
                else      ((u16*)Cd)[o] = f2bf(acc[i][j][r]);
            }
        }
    }
}

// 128x64 F@H^T tile over K-range [y*256,(y+1)*256). Fs:128x64, Hs:64x64 LDS.
__device__ __forceinline__ void hop_tile(
    const u16* __restrict__ Fb, const u16* __restrict__ Hb,
    int y, int tmt, float* __restrict__ Pd, u16* Fs, u16* Hs)
{
    int tm = tmt * 128, kb = y * 256;
    int t = threadIdx.x, lane = t & 63, w = t >> 6;
    int fr = lane & 15, q = lane >> 4, m7 = fr & 7;
    int subrow = lane >> 3, cch = (lane & 7) ^ subrow;

    const u16* fg[4]; u16* fl[4]; const u16* hg[2]; u16* hl[2];
    #pragma unroll
    for (int i = 0; i < 4; i++) {
        int r = i * 32 + w * 8 + subrow;
        fg[i] = Fb + (long)(tm + r) * 1024 + cch * 8;
        fl[i] = Fs + (i * 32 + w * 8) * 64;
    }
    #pragma unroll
    for (int i = 0; i < 2; i++) {
        int r = i * 32 + w * 8 + subrow;
        hg[i] = Hb + (long)r * 1024 + cch * 8;
        hl[i] = Hs + (i * 32 + w * 8) * 64;
    }

    v4f acc[2][4];
    #pragma unroll
    for (int i = 0; i < 2; i++)
        #pragma unroll
        for (int j = 0; j < 4; j++) {
            acc[i][j][0] = 0.f; acc[i][j][1] = 0.f; acc[i][j][2] = 0.f; acc[i][j][3] = 0.f;
        }

    for (int k0 = kb; k0 < kb + 256; k0 += 64) {
        __syncthreads();
        #pragma unroll
        for (int i = 0; i < 4; i++) gload16(fg[i] + k0, fl[i]);
        #pragma unroll
        for (int i = 0; i < 2; i++) gload16(hg[i] + k0, hl[i]);
        __syncthreads();
        v8s af[2][2], bfr[2][4];
        #pragma unroll
        for (int h = 0; h < 2; h++) {
            int ca = (((h << 2) + q) ^ m7) << 3;
            #pragma unroll
            for (int s = 0; s < 2; s++)
                af[h][s] = *(const v8s*)(Fs + (w * 32 + s * 16 + fr) * 64 + ca);
            #pragma unroll
            for (int s = 0; s < 4; s++)
                bfr[h][s] = *(const v8s*)(Hs + (s * 16 + fr) * 64 + ca);
        }
        #pragma unroll
        for (int h = 0; h < 2; h++)
            #pragma unroll
            for (int i = 0; i < 2; i++)
                #pragma unroll
                for (int j = 0; j < 4; j++)
                    acc[i][j] = __builtin_amdgcn_mfma_f32_16x16x32_bf16(af[h][i], bfr[h][j], acc[i][j], 0, 0, 0);
    }
    #pragma unroll
    for (int i = 0; i < 2; i++) {
        int rowb = tm + w * 32 + i * 16 + q * 4;
        #pragma unroll
        for (int j = 0; j < 4; j++) {
            int col = j * 16 + fr;
            #pragma unroll
            for (int r = 0; r < 4; r++)
                Pd[(long)(rowb + r) * 64 + col] = acc[i][j][r];
        }
    }
}

// fused prob_log/sigmoid/row-norm for one row (wave-collective, 64 lanes).
// Vectorized: lane handles 16 CONTIGUOUS columns [lane*16, lane*16+16).
__device__ __forceinline__ void fused_row(
    const u16* __restrict__ r1, const u16* __restrict__ r2, const u16* __restrict__ r3,
    float w0, float w1, float w2, float b0, u16* __restrict__ Frow, int lane)
{
    int base = lane << 4;
    union U { uint4 v; u16 s[8]; };
    U a[2], b[2], c[2];
    a[0].v = *(const uint4*)(r1 + base); a[1].v = *(const uint4*)(r1 + base + 8);
    b[0].v = *(const uint4*)(r2 + base); b[1].v = *(const uint4*)(r2 + base + 8);
    c[0].v = *(const uint4*)(r3 + base); c[1].v = *(const uint4*)(r3 + base + 8);
    float m1[16], m2[16], m3[16];
    float s1 = 0.f, s2 = 0.f, s3 = 0.f;
    #pragma unroll
    for (int h = 0; h < 2; h++)
        #pragma unroll
        for (int e = 0; e < 8; e++) {
            int k = h * 8 + e;
            m1[k] = bf2f(a[h].s[e]); m2[k] = bf2f(b[h].s[e]); m3[k] = bf2f(c[h].s[e]);
            s1 += m1[k]; s2 += m2[k]; s3 += m3[k];
        }
    #pragma unroll
    for (int o = 1; o < 64; o <<= 1) {
        s1 += __shfl_xor(s1, o); s2 += __shfl_xor(s2, o); s3 += __shfl_xor(s3, o);
    }
    float i1 = 1.f / (s1 + 1e-6f), i2 = 1.f / (s2 + 1e-6f), i3 = 1.f / (s3 + 1e-6f);
    float sig[16];
    float ssum = 0.f;
    #pragma unroll
    for (int k = 0; k < 16; k++) {
        float p1 = fminf(fmaxf(m1[k] * i1, 1e-6f), 1.0f - 1e-6f);
        float p2 = fminf(fmaxf(m2[k] * i2, 1e-6f), 1.0f - 1e-6f);
        float p3 = fminf(fmaxf(m3[k] * i3, 1e-6f), 1.0f - 1e-6f);
        float l1 = __logf(p1 / (1.0f - p1 + 1e-6f));
        float l2 = __logf(p2 / (1.0f - p2 + 1e-6f));
        float l3 = __logf(p3 / (1.0f - p3 + 1e-6f));
        float lg = b0 + w0 * l1 + w1 * l2 + w2 * l3;
        float sg = 1.0f / (1.0f + __expf(-lg));
        sig[k] = sg; ssum += sg;
    }
    #pragma unroll
    for (int o = 1; o < 64; o <<= 1) ssum += __shfl_xor(ssum, o);
    float inv = 1.0f / (ssum + 1e-6f);
    U o0, o1;
    #pragma unroll
    for (int e = 0; e < 8; e++) { o0.s[e] = f2bf(sig[e] * inv); o1.s[e] = f2bf(sig[8 + e] * inv); }
    *(uint4*)(Frow + base) = o0.v;
    *(uint4*)(Frow + base + 8) = o1.v;
}

// ---------------------------------------------------------------------------
// Generation-1: AAt (upper 36, reg-mirrored), AtA (same), A2 = A*A (full 64).
// 1D grid 1088 = 8 batches x 136 jobs, batch = blockIdx.x & 7 (XCD locality).
// ---------------------------------------------------------------------------
__global__ __launch_bounds__(256) void gemm_link1(
    const u16* __restrict__ A, const u16* __restrict__ AT,
    u16* __restrict__ AAt, u16* __restrict__ AtA, u16* __restrict__ A2)
{
    __shared__ u16 Xs[128 * 64];
    __shared__ u16 Ys[128 * 64];
    const long SSq = (long)SS * SS;
    int b = blockIdx.x & 7;
    int job = blockIdx.x >> 3;
    const u16* Xb; const u16* Yb; u16* Cd;
    int ti, tj, mir;
    if (job < 72) {
        int tt = job < 36 ? job : job - 36;
        ti = 0;
        while (tt >= 8 - ti) { tt -= 8 - ti; ti++; }
        tj = ti + tt;
        mir = (ti != tj);
        if (job < 36) { Xb = A  + b * SSq; Yb = Xb; Cd = AAt + b * SSq; }
        else          { Xb = AT + b * SSq; Yb = Xb; Cd = AtA + b * SSq; }
    } else {
        int jj = job - 72;
        ti = jj >> 3; tj = jj & 7; mir = 0;
        Xb = A + b * SSq; Yb = AT + b * SSq; Cd = A2 + b * SSq;   // A2 = A*(AT)^T = A*A
    }
    tile_1024(Xb, Yb, Cd, ti * 128, tj * 128, Xs, Ys, mir);
}

// ---------------------------------------------------------------------------
// Gen-2 symmetric pair (576 blocks, reg-mirrored) + hop-0 GEMM tail
// (256 short MFMA blocks, split-K=4). Homogeneous MFMA work only.
// ---------------------------------------------------------------------------
__global__ __launch_bounds__(256) void gemm_link2h0(
    const u16* __restrict__ AAt, const u16* __restrict__ AtA,
    u16* __restrict__ AAt2, u16* __restrict__ AtA2,
    const u16* __restrict__ F0, const u16* __restrict__ hopVT,
    float* __restrict__ Pa, float* __restrict__ Pb)
{
    __shared__ u16 Xs[128 * 64];
    __shared__ u16 Ys[128 * 64];
    const long SSq = (long)SS * SS;
    int bx = blockIdx.x;
    if (bx < 576) {
        int z = bx & 15;
        int tt = bx >> 4, ti = 0;
        while (tt >= 8 - ti) { tt -= 8 - ti; ti++; }
        int tj = ti + tt;
        const u16* Xb = (z < 8 ? AAt : AtA) + (long)(z & 7) * SSq;
        u16* Cd = (z < 8 ? AAt2 : AtA2) + (long)(z & 7) * SSq;
        tile_1024(Xb, Xb, Cd, ti * 128, tj * 128, Xs, Ys, ti != tj);
    } else {
        int j = bx - 576;                  // 0..255
        int y = j >> 6, rest = j & 63;
        int tmt = rest >> 3, b = rest & 7;
        float* Pd = (y < 2 ? Pa + (long)y * 16 * 65536 : Pb + (long)(y - 2) * 16 * 65536)
                    + (long)b * 65536;                    // hop=0
        hop_tile(F0 + (long)b * SSq, hopVT + (long)b * 65536, y, tmt, Pd, Xs, Ys);
    }
}

// hop-1 GEMM standalone, split-K=4: grid 256.
__global__ __launch_bounds__(256) void gemm_hop1(
    const u16* __restrict__ F1, const u16* __restrict__ hopVT,
    float* __restrict__ Pa, float* __restrict__ Pb)
{
    __shared__ u16 Fs[128 * 64];
    __shared__ u16 Hs[64 * 64];
    const long SSq = (long)SS * SS;
    int j = blockIdx.x;
    int y = j >> 6, rest = j & 63;
    int tmt = rest >> 3, b = rest & 7;
    float* Pd = (y < 2 ? Pa + (long)y * 16 * 65536 : Pb + (long)(y - 2) * 16 * 65536)
                + (long)(8 + b) * 65536;                  // hop=1
    hop_tile(F1 + (long)b * SSq, hopVT + (long)(8 + b) * 65536, y, tmt, Pd, Fs, Hs);
}

// ---------------------------------------------------------------------------
// Generic batched NT GEMM (projection + final): C[z] = X[z](MxK) * Y[z]^T(NxK)
// ---------------------------------------------------------------------------
__global__ __launch_bounds__(256) void gemm_nt(
    const u16* __restrict__ X, long sx,
    const u16* __restrict__ Y, long sy,
    void* __restrict__ Cv, long sc,
    int M, int N, int K, int cf32)
{
    __shared__ u16 Xs[128 * 64];
    __shared__ u16 Ys[128 * 64];
    const u16* Xb = X + (long)blockIdx.z * sx;
    const u16* Yb = Y + (long)blockIdx.z * sy;
    int tm = blockIdx.x * 128, tn = blockIdx.y * 128;
    int t = threadIdx.x, lane = t & 63, w = t >> 6;
    int wm = (w & 1) << 6, wn = (w >> 1) << 6;
    int fr = lane & 15, q = lane >> 4, m7 = fr & 7;
    int subrow = lane >> 3, cch = (lane & 7) ^ subrow;

    const u16* xg[4]; const u16* yg[4]; u16* xl[4]; u16* yl[4];
    #pragma unroll
    for (int i = 0; i < 4; i++) {
        int r = i * 32 + w * 8 + subrow;
        xg[i] = Xb + (long)(tm + r) * K + cch * 8;
        yg[i] = Yb + (long)(tn + r) * K + cch * 8;
        xl[i] = Xs + (i * 32 + w * 8) * 64;
        yl[i] = Ys + (i * 32 + w * 8) * 64;
    }

    v4f acc[4][4];
    #pragma unroll
    for (int i = 0; i < 4; i++)
        #pragma unroll
        for (int j = 0; j < 4; j++) {
            acc[i][j][0] = 0.f; acc[i][j][1] = 0.f; acc[i][j][2] = 0.f; acc[i][j][3] = 0.f;
        }

    for (int k0 = 0; k0 < K; k0 += 64) {
        __syncthreads();
        #pragma unroll
        for (int i = 0; i < 4; i++) { gload16(xg[i] + k0, xl[i]); gload16(yg[i] + k0, yl[i]); }
        __syncthreads();
        v8s af[2][4], bfr[2][4];
        #pragma unroll
        for (int h = 0; h < 2; h++) {
            int ca = (((h << 2) + q) ^ m7) << 3;
            #pragma unroll
            for (int s = 0; s < 4; s++) {
                af[h][s]  = *(const v8s*)(Xs + (wm + s * 16 + fr) * 64 + ca);
                bfr[h][s] = *(const v8s*)(Ys + (wn + s * 16 + fr) * 64 + ca);
            }
        }
        #pragma unroll
        for (int h = 0; h < 2; h++)
            #pragma unroll
            for (int i = 0; i < 4; i++)
                #pragma unroll
                for (int j = 0; j < 4; j++)
                    acc[i][j] = __builtin_amdgcn_mfma_f32_16x16x32_bf16(af[h][i], bfr[h][j], acc[i][j], 0, 0, 0);
    }
    long cb = (long)blockIdx.z * sc;
    #pragma unroll
    for (int i = 0; i < 4; i++) {
        int rowb = tm + wm + i * 16 + q * 4;
        #pragma unroll
        for (int j = 0; j < 4; j++) {
            int col = tn + wn + j * 16 + fr;
            #pragma unroll
            for (int r = 0; r < 4; r++) {
                long o = cb + (long)(rowb + r) * N + col;
                if (cf32) ((float*)Cv)[o] = acc[i][j][r];
                else      ((u16*)Cv)[o] = f2bf(acc[i][j][r]);
            }
        }
    }
}

// ---------------------------------------------------------------------------
// Merged: QK^T scores (512 blocks, fp32) + hopV projection (64 blocks, bf16)
// ---------------------------------------------------------------------------
__global__ __launch_bounds__(256) void k_qk_hopv(
    const u16* __restrict__ Qb, const u16* __restrict__ Kb,
    const u16* __restrict__ Vb, const u16* __restrict__ hopWb,
    float* __restrict__ scores, u16* __restrict__ hopvC)
{
    __shared__ u16 Xs[128 * 64];
    __shared__ u16 Ys[128 * 64];
    const long SSq = (long)SS * SS;
    const long SD = (long)SS * DD;
    int bx = blockIdx.x;
    if (bx < 512) {
        int z = bx & 7;
        int tt = bx >> 3;
        int tm = (tt >> 3) * 128, tn = (tt & 7) * 128;
        tile_k64(Qb + z * SD + (long)tm * 64, Kb + z * SD + (long)tn * 64,
                 scores + z * SSq + (long)tm * 1024 + tn, 1024, 1, Xs, Ys);
    } else {
        int tm = (bx - 512) * 128;
        tile_k64(Vb + (long)tm * 64, hopWb,
                 hopvC + (long)tm * 128, 128, 0, Xs, Ys);
    }
}

// ---------------------------------------------------------------------------
// Merged: softmax (2048 blocks) + hopVT transposes (256 blocks)
// ---------------------------------------------------------------------------
__global__ __launch_bounds__(256) void k_sm_hvt(
    const float* __restrict__ scores, const float* __restrict__ btab,
    const float* __restrict__ temp, u16* __restrict__ A,
    const u16* __restrict__ hopvC, u16* __restrict__ hopVT)
{
    __shared__ __align__(16) float smf[3969];   // 15876 B
    int bx = blockIdx.x;
    int t = threadIdx.x;
    if (bx < 2048) {
        for (int i = t; i < 3969; i += 256) smf[i] = btab[i];
        __syncthreads();
        int lane = t & 63, w = t >> 6;
        long row = (long)bx * 4 + w;
        int i = (int)(row & 1023);
        int ih = i >> 5, iw = i & 31;
        float inv_t = 1.0f / fmaxf(temp[0], 0.1f);
        const float* srow = scores + row * 1024;
        float sc[16];
        float m = -1e30f;
        #pragma unroll
        for (int c = 0; c < 16; c++) {
            int j = c * 64 + lane;
            int jh = j >> 5, jw = j & 31;
            float pb = smf[(ih - jh + 31) * 63 + (iw - jw + 31)];
            float s = (srow[j] * 0.125f + pb) * inv_t;
            sc[c] = s; m = fmaxf(m, s);
        }
        #pragma unroll
        for (int o = 1; o < 64; o <<= 1) m = fmaxf(m, __shfl_xor(m, o));
        float sum = 0.f;
        #pragma unroll
        for (int c = 0; c < 16; c++) { sc[c] = __expf(sc[c] - m); sum += sc[c]; }
        #pragma unroll
        for (int o = 1; o < 64; o <<= 1) sum += __shfl_xor(sum, o);
        float inv = 1.0f / sum;
        #pragma unroll
        for (int c = 0; c < 16; c++) A[row * 1024 + c * 64 + lane] = f2bf(sc[c] * inv);
    } else {
        u16* tile = (u16*)smf;                 // 64*72 u16 = 9216 B
        int ex = bx - 2048;                    // 0..255
        int hop = ex >> 7, rem = ex & 127;
        int z = rem & 7, i0 = (rem >> 3) * 64;
        const u16* s = hopvC + (long)z * (1024 * 128) + hop * 64;
        u16* d = hopVT + (long)(hop * 8 + z) * 65536;
        int r = t >> 2, c0 = (t & 3) << 4;
        #pragma unroll
        for (int p = 0; p < 2; p++) {
            int c = c0 + p * 8;
            uint4 v = *(const uint4*)(s + (long)(i0 + r) * 128 + c);
            *(uint4*)(&tile[r * 72 + c]) = v;
        }
        __syncthreads();
        #pragma unroll
        for (int p = 0; p < 2; p++) {
            uint4 ov; u16* po = (u16*)&ov;
            #pragma unroll
            for (int e = 0; e < 8; e++) po[e] = tile[(c0 + p * 8 + e) * 72 + r];
            *(uint4*)(d + (long)r * 1024 + i0 + c0 + p * 8) = ov;
        }
    }
}

// fused hop-0: 2048 blocks, 1 row/wave
__global__ __launch_bounds__(256) void k_fused0(
    const u16* __restrict__ A, const u16* __restrict__ AAt,
    const u16* __restrict__ AtA, const float* __restrict__ fw,
    const float* __restrict__ fbv, u16* __restrict__ F0)
{
    int lane = threadIdx.x & 63, w = threadIdx.x >> 6;
    float w0 = fw[0], w1 = fw[1], w2 = fw[2], b0 = fbv[0];
    long row = (long)blockIdx.x * 4 + w;
    fused_row(A + row * 1024, AAt + row * 1024, AtA + row * 1024,
              w0, w1, w2, b0, F0 + row * 1024, lane);
}

// fused hop-1: 2048 blocks, 1 row/wave
__global__ __launch_bounds__(256) void k_fused1(
    const u16* __restrict__ A2, const u16* __restrict__ AAt2,
    const u16* __restrict__ AtA2, const float* __restrict__ fw,
    const float* __restrict__ fbv, u16* __restrict__ F1)
{
    int lane = threadIdx.x & 63, w = threadIdx.x >> 6;
    float w0 = fw[3], w1 = fw[4], w2 = fw[5], b0 = fbv[1];
    long row = (long)blockIdx.x * 4 + w;
    fused_row(A2 + row * 1024, AAt2 + row * 1024, AtA2 + row * 1024,
              w0, w1, w2, b0, F1 + row * 1024, lane);
}

// pack x + weights to bf16 (merged)
__global__ __launch_bounds__(256) void k_pack(
    const float* __restrict__ x, const float* __restrict__ Wq,
    const float* __restrict__ Wk, const float* __restrict__ Wv,
    const float* __restrict__ gW, const float* __restrict__ hopW,
    const float* __restrict__ outW, u16* __restrict__ xb,
    u16* __restrict__ wpack, u16* __restrict__ hopWb, u16* __restrict__ outWb)
{
    int bx = blockIdx.x;
    if (bx < 4096) {
        long i = (long)bx * 256 + threadIdx.x;
        float4 v = ((const float4*)x)[i];
        ushort4 o;
        o.x = f2bf(v.x); o.y = f2bf(v.y); o.z = f2bf(v.z); o.w = f2bf(v.w);
        ((ushort4*)xb)[i] = o;
    } else {
        int idx = (bx - 4096) * 256 + threadIdx.x;
        if (idx < 131072) {
            int r = idx >> 9, c = idx & 511;
            float v = 0.f;
            if (r < 64)       v = Wq[r * 512 + c];
            else if (r < 128) v = Wk[(r - 64) * 512 + c];
            else if (r < 192) v = Wv[(r - 128) * 512 + c];
            else if (r < 194) v = gW[(r - 192) * 512 + c];
            wpack[idx] = f2bf(v);
        } else if (idx < 131072 + 8192) {
            int i = idx - 131072;
            hopWb[i] = f2bf(hopW[i]);
        } else if (idx < 131072 + 8192 + 32768) {
            int i = idx - 131072 - 8192;
            outWb[i] = f2bf(outW[i]);
        }
    }
}

// RoPE + gate softmax + Vb
__global__ __launch_bounds__(256) void k_rope(
    const float* __restrict__ QKVG, const float* __restrict__ gateb,
    u16* __restrict__ Qb, u16* __restrict__ Kb, u16* __restrict__ Vb,
    float* __restrict__ gate)
{
    int t = threadIdx.x, l = t & 63, w = t >> 6;
    long row = (long)blockIdx.x * 4 + w;
    int spos = (int)(row & (SS - 1));
    const float* base = QKVG + row * 256;
    float q = base[l], k = base[64 + l], v = base[128 + l];
    float qp = __shfl_xor(q, 32), kp = __shfl_xor(k, 32);
    float sgn = (l < 32) ? -1.f : 1.f;
    int f = l & 31;
    float ang = (float)spos * exp2f(-(float)f * (13.287712379549449f / 32.0f));
    float cs = cosf(ang), sn = sinf(ang);
    Qb[row * 64 + l] = f2bf(q * cs + sgn * qp * sn);
    Kb[row * 64 + l] = f2bf(k * cs + sgn * kp * sn);
    Vb[row * 64 + l] = f2bf(v);
    if (l < 2) {
        float g0 = base[192] + gateb[0], g1 = base[193] + gateb[1];
        float m = fmaxf(g0, g1);
        float e0 = __expf(g0 - m), e1 = __expf(g1 - m);
        gate[row * 2 + l] = ((l == 0) ? e0 : e1) / (e0 + e1);
    }
}

// generic bf16 transpose (A -> AT)
__global__ __launch_bounds__(256) void k_transpose(
    const u16* __restrict__ src, u16* __restrict__ dst,
    int srs, int drs, long sbs, long dbs)
{
    __shared__ u16 tile[64 * 72];
    const u16* s = src + (long)blockIdx.z * sbs;
    u16* d = dst + (long)blockIdx.z * dbs;
    int i0 = blockIdx.x * 64, j0 = blockIdx.y * 64;
    int t = threadIdx.x;
    int r = t >> 2, c0 = (t & 3) << 4;
    #pragma unroll
    for (int p = 0; p < 2; p++) {
        int c = c0 + p * 8;
        uint4 v = *(const uint4*)(s + (long)(i0 + r) * srs + j0 + c);
        *(uint4*)(&tile[r * 72 + c]) = v;
    }
    __syncthreads();
    #pragma unroll
    for (int p = 0; p < 2; p++) {
        uint4 ov;
        u16* po = (u16*)&ov;
        #pragma unroll
        for (int e = 0; e < 8; e++) po[e] = tile[(c0 + p * 8 + e) * 72 + r];
        *(uint4*)(d + (long)(j0 + r) * drs + i0 + c0 + p * 8) = ov;
    }
}

// sum split-K=4 partials, gate-combine -> comb bf16 [8192][64]
__global__ __launch_bounds__(256) void k_combine(
    const float* __restrict__ Pa, const float* __restrict__ Pb,
    const float* __restrict__ gate, u16* __restrict__ comb)
{
    long idx = (long)blockIdx.x * 256 + threadIdx.x;   // 8192*64
    long srow = idx >> 6;
    int b = (int)(srow >> 10);
    long o = (long)(srow & 1023) * 64 + (idx & 63);
    float h0 = Pa[(long)b * 65536 + o] + Pa[(long)(16 + b) * 65536 + o]
             + Pb[(long)b * 65536 + o] + Pb[(long)(16 + b) * 65536 + o];
    float h1 = Pa[(long)(8 + b) * 65536 + o] + Pa[(long)(24 + b) * 65536 + o]
             + Pb[(long)(8 + b) * 65536 + o] + Pb[(long)(24 + b) * 65536 + o];
    float g0 = gate[srow * 2], g1 = gate[srow * 2 + 1];
    comb[idx] = f2bf(h0 * g0 + h1 * g1);
}

// ---------------------------------------------------------------------------
extern "C" void kernel_launch(void* const* d_in, const int* in_sizes, int n_in,
                              void* d_out, int out_size, void* d_ws, size_t ws_size,
                              hipStream_t stream) {
    const float* x    = (const float*)d_in[0];
    const float* Wq   = (const float*)d_in[1];
    const float* Wk   = (const float*)d_in[2];
    const float* Wv   = (const float*)d_in[3];
    const float* btab = (const float*)d_in[4];
    const float* fw   = (const float*)d_in[5];
    const float* fbv  = (const float*)d_in[6];
    const float* hopW = (const float*)d_in[7];
    const float* gW   = (const float*)d_in[8];
    const float* gb   = (const float*)d_in[9];
    const float* outW = (const float*)d_in[10];
    const float* temp = (const float*)d_in[11];
    float* out = (float*)d_out;

    char* wsb = (char*)d_ws;
    size_t off = 0;
    auto take = [&](size_t n) { char* p = wsb + off; off += (n + 255) & ~(size_t)255; return p; };
    u16* Qb      = (u16*)take(8192L * 64 * 2);
    u16* Kb      = (u16*)take(8192L * 64 * 2);
    u16* Vb      = (u16*)take(8192L * 64 * 2);
    float* gate  = (float*)take(8192L * 2 * 4);
    u16* wpack   = (u16*)take(256L * 512 * 2);
    u16* hopWb   = (u16*)take(2L * 64 * 64 * 2);
    u16* outWb   = (u16*)take(512L * 64 * 2);
    u16* hopvC   = (u16*)take(8192L * 128 * 2);      // [s][hop*64+e]
    u16* hopVT   = (u16*)take(2L * 8 * 64 * 1024 * 2);
    float* Pa    = (float*)take(2L * 16 * 65536 * 4);     // split-K partials y=0,1
    u16* comb    = (u16*)take(8192L * 64 * 2);
    float* scoresF = (float*)take(8L * 1024 * 1024 * 4);  // 32 MB region
    float* QKVG  = (float*)scoresF;                   // alias: dead before scores
    u16* F0      = (u16*)scoresF;                     // alias: scores dead before F0
    u16* F1      = (u16*)scoresF + 8L * 1024 * 1024;  // second 16 MB of region
    u16* A       = (u16*)take(8L * 1024 * 1024 * 2);
    u16* xb      = (u16*)A;                           // alias: dead before A
    u16* AT      = (u16*)take(8L * 1024 * 1024 * 2);
    float* Pb    = (float*)AT;                        // alias: AT dead after link1
    u16* AAt     = (u16*)take(8L * 1024 * 1024 * 2);
    u16* AtA     = (u16*)take(8L * 1024 * 1024 * 2);
    u16* A2      = (u16*)take(8L * 1024 * 1024 * 2);
    u16* AAt2    = (u16*)take(8L * 1024 * 1024 * 2);
    u16* AtA2    = (u16*)take(8L * 1024 * 1024 * 2);
    (void)ws_size; (void)in_sizes; (void)n_in; (void)out_size;

    const long SSq = (long)SS * SS;

    // 1. pack inputs (merged)
    k_pack<<<4768, 256, 0, stream>>>(x, Wq, Wk, Wv, gW, hopW, outW, xb, wpack, hopWb, outWb);
    // 2. fused projection: QKVG[8192][256] = xb @ wpack^T (fp32)
    gemm_nt<<<dim3(64, 2, 1), 256, 0, stream>>>(xb, 0, wpack, 0, QKVG, 0, 8192, 256, 512, 1);
    // 3. rope + gate + Vb
    k_rope<<<2048, 256, 0, stream>>>(QKVG, gb, Qb, Kb, Vb, gate);
    // 4. scores = Q K^T (fp32) + hopvC = Vb @ hopWb^T (merged)
    k_qk_hopv<<<576, 256, 0, stream>>>(Qb, Kb, Vb, hopWb, scoresF, hopvC);
    // 5. softmax -> A + hopVT transposes (merged)
    k_sm_hvt<<<2304, 256, 0, stream>>>(scoresF, btab, temp, A, hopvC, hopVT);
    // 6. AT
    k_transpose<<<dim3(16, 16, 8), 256, 0, stream>>>(A, AT, 1024, 1024, SSq, SSq);
    // 7. generation-1: AAt, AtA (reg-mirrored) + A2 (full)
    gemm_link1<<<1088, 256, 0, stream>>>(A, AT, AAt, AtA, A2);
    // 8. fused hop-0 -> F0
    k_fused0<<<2048, 256, 0, stream>>>(A, AAt, AtA, fw, fbv, F0);
    // 9. gen-2 sym pair (reg-mirrored) + hop-0 GEMM tail
    gemm_link2h0<<<832, 256, 0, stream>>>(AAt, AtA, AAt2, AtA2, F0, hopVT, Pa, Pb);
    // 10. fused hop-1 -> F1
    k_fused1<<<2048, 256, 0, stream>>>(A2, AAt2, AtA2, fw, fbv, F1);
    // 11. hop-1 GEMM
    gemm_hop1<<<256, 256, 0, stream>>>(F1, hopVT, Pa, Pb);
    // 12. combine + output projection
    k_combine<<<2048, 256, 0, stream>>>(Pa, Pb, gate, comb);
    gemm_nt<<<dim3(64, 4, 1), 256, 0, stream>>>(comb, 0, outWb, 0, out, 0, 8192, 512, 64, 1);
}